// Round 15
// baseline (221.525 us; speedup 1.0000x reference)
//
#include <hip/hip_runtime.h>
#include <hip/hip_bf16.h>
#include <stdint.h>

// ---------------------------------------------------------------------------
// OEQTensorProduct: x[N,576] (64x{0e,1o,2e}) (x) y[N,9] ({0e,1o,2e}) -> out[N,576]
// 1-wave blocks, ITER=4 octets per block, grid 3125.
// Compute core & store structure = R14 (175.7us, proven @2.4e-4).
// R15 theory: wave lifetime ~25-31us across ALL prior structures = front-end
// instruction streaming (~40KB unrolled body > 32KB I$, ~15cyc/instr at L2
// fetch latency). Fix: (1) ks-loop '#pragma unroll 1' with per-iteration
// B loads halves the body to ~16KB (< I$); (2) ITER=4 loop reuses the warm
// body 4x per wave. Everything data-side unchanged.
// ---------------------------------------------------------------------------

#define NEDGES 100000
#define NE_W   8                      // edges per octet
#define ITER   4                      // octets per wave
#define NBLK   (NEDGES/(NE_W*ITER))   // 3125 one-wave blocks

typedef short    short8 __attribute__((ext_vector_type(8)));
typedef float    f32x4  __attribute__((ext_vector_type(4)));
typedef uint32_t u32x4  __attribute__((ext_vector_type(4)));

// ---------------- compile-time Wigner-3j (real basis) tables ----------------
constexpr int L1A[11] = {0,0,0,1,1,1,1,2,2,2,2};
constexpr int L2A[11] = {0,1,2,0,1,1,2,0,1,2,2};
constexpr int L3A[11] = {0,1,2,1,0,2,1,2,1,0,2};

constexpr double cfact(int n){ double r=1.0; for(int i=2;i<=n;++i) r*=(double)i; return r; }
constexpr double csqrt(double x){ if(x<=0.0) return 0.0; double g = x>1.0?x:1.0;
                                 for(int i=0;i<80;++i) g=0.5*(g+x/g); return g; }
constexpr int imax2(int a,int b){return a>b?a:b;}
constexpr int imin2(int a,int b){return a<b?a:b;}

constexpr double su2_cg(int j1,int j2,int j3,int m1,int m2,int m3){
  if(m3 != m1+m2) return 0.0;
  int vmin = imax2(imax2(-j1+j2+m3, -j1+m1), 0);
  int vmax = imin2(imin2(j2+j3+m1, j3-j1+j2), j3+m3);
  double c = csqrt((double)(2*j3+1)*cfact(j3+j1-j2)*cfact(j3-j1+j2)*cfact(j1+j2-j3)
                   *cfact(j3+m3)*cfact(j3-m3)
                   /(cfact(j1+j2+j3+1)*cfact(j1-m1)*cfact(j1+m1)*cfact(j2-m2)*cfact(j2+m2)));
  double s=0.0;
  for(int v=vmin; v<=vmax; ++v){
    double sg = ((v+j2+m2)&1)? -1.0 : 1.0;
    s += sg*cfact(j2+j3+m1-v)*cfact(j1-m1+v)
         /(cfact(v)*cfact(j3-j1+j2-v)*cfact(j3+m3-v)*cfact(j1-j2-m3+v));
  }
  return c*s;
}

struct Cplx{ double re, im; };
struct Q55 { Cplx q[5][5]; };

constexpr Q55 change_basis(int l){
  Q55 Q{};
  const double is2 = 1.0/csqrt(2.0);
  for(int m=-l;m<0;++m){
    Q.q[l+m][l-m].re =  is2;
    Q.q[l+m][l+m].im = -is2;
  }
  Q.q[l][l].re = 1.0;
  for(int m=1;m<=l;++m){
    double s = (m&1)? -1.0 : 1.0;
    Q.q[l+m][l+m].re = s*is2;
    Q.q[l+m][l-m].im = s*is2;
  }
  for(int i=0;i<5;++i) for(int j=0;j<5;++j){
    double re=Q.q[i][j].re, im=Q.q[i][j].im;
    if(l==1){ Q.q[i][j].re = im;  Q.q[i][j].im = -re; }
    else if(l==2){ Q.q[i][j].re = -re; Q.q[i][j].im = -im; }
  }
  return Q;
}

struct Tbl {
  double C[11][5][5][5];   // [I][p][q][r]
  double alpha[11];
};

constexpr Tbl build_tbl(){
  Tbl T{};
  for(int I=0;I<11;++I){
    const int l1=L1A[I], l2=L2A[I], l3=L3A[I];
    const int D1=2*l1+1, D2=2*l2+1, D3=2*l3+1;
    double cg[5][5][5]{};
    for(int a=0;a<D1;++a)for(int b=0;b<D2;++b){
      int m3 = (a-l1)+(b-l2);
      if(m3>=-l3 && m3<=l3) cg[a][b][l3+m3] = su2_cg(l1,l2,l3,a-l1,b-l2,m3);
    }
    Q55 q1 = change_basis(l1), q2 = change_basis(l2), q3 = change_basis(l3);
    Cplx T1[5][5][5]{};
    for(int i=0;i<D1;++i)for(int b=0;b<D2;++b)for(int c=0;c<D3;++c){
      double re=0,im=0;
      for(int a=0;a<D1;++a){ re += q1.q[a][i].re*cg[a][b][c]; im += q1.q[a][i].im*cg[a][b][c]; }
      T1[i][b][c].re=re; T1[i][b][c].im=im;
    }
    Cplx T2[5][5][5]{};
    for(int i=0;i<D1;++i)for(int j=0;j<D2;++j)for(int c=0;c<D3;++c){
      double re=0,im=0;
      for(int b=0;b<D2;++b){
        double qr=q2.q[b][j].re, qi=q2.q[b][j].im;
        re += qr*T1[i][b][c].re - qi*T1[i][b][c].im;
        im += qr*T1[i][b][c].im + qi*T1[i][b][c].re;
      }
      T2[i][j][c].re=re; T2[i][j][c].im=im;
    }
    double nrm2 = 0.0;
    for(int i=0;i<D1;++i)for(int j=0;j<D2;++j)for(int k=0;k<D3;++k){
      double re=0;
      for(int c=0;c<D3;++c){
        double qr=q3.q[c][k].re, qi=-q3.q[c][k].im;   // conj
        re += qr*T2[i][j][c].re - qi*T2[i][j][c].im;
      }
      T.C[I][i][j][k] = re; nrm2 += re*re;
    }
    double nrm = csqrt(nrm2);
    if(nrm > 0.0)
      for(int i=0;i<D1;++i)for(int j=0;j<D2;++j)for(int k=0;k<D3;++k) T.C[I][i][j][k] /= nrm;
    const int fan = (l3==0)?192:256;
    T.alpha[I] = csqrt((double)(2*l3+1)/(double)fan);
  }
  return T;
}

constexpr Tbl TBL = build_tbl();

__device__ const float c_alpha[11] = {
  (float)TBL.alpha[0],(float)TBL.alpha[1],(float)TBL.alpha[2],(float)TBL.alpha[3],
  (float)TBL.alpha[4],(float)TBL.alpha[5],(float)TBL.alpha[6],(float)TBL.alpha[7],
  (float)TBL.alpha[8],(float)TBL.alpha[9],(float)TBL.alpha[10]
};

// ---------------- device helpers ----------------
__device__ __forceinline__ uint16_t f2bf(float f){      // fp32 -> bf16 RNE
  uint32_t u = __float_as_uint(f);
  return (uint16_t)((u + 0x7fffu + ((u>>16)&1u)) >> 16);
}
// compiler-recognized packed bf16 convert (emits v_cvt_pk_bf16_f32, RNE)
__device__ __forceinline__ uint32_t pk2c(float a, float b){
  __hip_bfloat162 h = __float22bfloat162_rn(float2{a,b});
  uint32_t r; __builtin_memcpy(&r, &h, 4); return r;
}

// ---------------- W pre-transform: Wt[I][w][u] = bf16(alpha_I * W[I][u][w]) ----
__global__ __launch_bounds__(256) void prep_w(const float* __restrict__ w,
                                              uint16_t* __restrict__ wt){
  int tid = blockIdx.x*256 + threadIdx.x;
  if(tid >= 11*4096) return;
  int I = tid >> 12;
  int rem = tid & 4095;
  int wo = rem >> 6, u = rem & 63;
  wt[tid] = f2bf(c_alpha[I] * w[(I<<12) + (u<<6) + wo]);
}

// ---------------------------------------------------------------------------
// xs LDS layout (9216 B): row rho = e*9 + pidx, 64 u's x 2B = 128 B;
// 16-B chunk s (u = s*8..s*8+7) stored at position s ^ (rho&7).
// ost LDS (1568 floats = 6272 B): per-kgroup tile, per-edge stride LEN+4
// (k0: 68, k1: 196) or, for k2, half-tiles of stride 164 (all == 4 mod 32).
// ---------------------------------------------------------------------------

// one instruction: ks as a REAL loop (unroll 1) with per-iteration B loads
// -> halves the emitted code per instruction (I$ residency is the point).
template<int I>
__device__ __forceinline__ void do_instr(f32x4* acc, const uint16_t* __restrict__ wt,
                                         const char* xsw, const float* yv,
                                         int lmod, int ldiv)
{
  constexpr int l1=L1A[I], l2=L2A[I], l3=L3A[I];
  constexpr int D1=2*l1+1, D2=2*l2+1, D3=2*l3+1;
  constexpr int PB=(l1==0)?0:((l1==1)?1:4);
  constexpr int QB=(l2==0)?0:((l2==1)?1:4);
  constexpr int MT=(D3+1)/2;

  // M[p][r] = sum_q C[p][q][r] * y[q]  (compile-time C, lane-local y)
  float M[D1][D3];
  #pragma unroll
  for(int p=0;p<D1;++p)
    #pragma unroll
    for(int r=0;r<D3;++r){
      float m=0.f;
      #pragma unroll
      for(int q=0;q<D2;++q){
        const float cc = (float)TBL.C[I][p][q][r];
        if(cc != 0.0f) m = fmaf(cc, yv[QB+q], m);
      }
      M[p][r]=m;
    }

  const bool lo8 = (lmod < 8);
  const int  e7  = lmod & 7;

  // per-tile M selection: lane's r = 2*mt + (lmod>=8), clamped on partial tile
  float ms[MT][D1];
  #pragma unroll
  for(int mt=0;mt<MT;++mt){
    const int rB = (2*mt+1 > D3-1) ? (D3-1) : (2*mt+1);
    #pragma unroll
    for(int p=0;p<D1;++p) ms[mt][p] = lo8 ? M[p][2*mt] : M[p][rB];
  }

  #pragma unroll 1
  for(int ks=0; ks<2; ++ks){
    // B-frags for this ks: 4 loads, compile-time nt indexing (no scratch)
    short8 B[4];
    #pragma unroll
    for(int nt=0;nt<4;++nt)
      B[nt] = *(const short8*)(wt + (I*64 + nt*16 + lmod)*64 + ks*32 + ldiv*8);
    __builtin_amdgcn_sched_barrier(0);   // issue loads before the VALU below

    // hoisted LDS reads + unpack (independent of mt)
    float xf[D1][8];
    #pragma unroll
    for(int p=0;p<D1;++p){
      const int rho  = e7*9 + PB + p;
      const int addr = rho*128 + (((ks*4+ldiv) ^ (rho&7))<<4);
      const u32x4 xv = *(const u32x4*)(xsw + addr);
      #pragma unroll
      for(int k=0;k<4;++k){
        xf[p][2*k]   = __uint_as_float(xv[k]<<16);
        xf[p][2*k+1] = __uint_as_float(xv[k]&0xffff0000u);
      }
    }
    #pragma unroll
    for(int mt=0;mt<MT;++mt){
      float zf[8];
      #pragma unroll
      for(int i=0;i<8;++i) zf[i]=0.f;
      #pragma unroll
      for(int p=0;p<D1;++p)
        #pragma unroll
        for(int i=0;i<8;++i) zf[i] = fmaf(ms[mt][p], xf[p][i], zf[i]);
      u32x4 av = { pk2c(zf[0],zf[1]), pk2c(zf[2],zf[3]),
                   pk2c(zf[4],zf[5]), pk2c(zf[6],zf[7]) };
      const short8 A = *(const short8*)&av;
      #pragma unroll
      for(int nt=0;nt<4;++nt)
        acc[mt*4+nt] = __builtin_amdgcn_mfma_f32_16x16x32_bf16(A, B[nt], acc[mt*4+nt], 0,0,0);
    }
  }
}

// full k-group (k0, k1): instr fold, padded-stride ost, 1-shot copy-out
template<int KOFF, int D3, int... Is>
__device__ __forceinline__ void kgroup(const uint16_t* __restrict__ wt, const char* xsw,
                                       const float* yv, float* __restrict__ outb,
                                       float* __restrict__ ost, int lane,
                                       int lmod, int ldiv)
{
  constexpr int MT     = (D3+1)/2;
  constexpr int LEN    = 64*D3;        // floats per edge in this k-group
  constexpr int STRIDE = LEN + 4;      // == 4 mod 32: conflict-free
  f32x4 acc[MT*4];
  #pragma unroll
  for(int i=0;i<MT*4;++i) acc[i] = (f32x4){0.f,0.f,0.f,0.f};

  (do_instr<Is>(acc, wt, xsw, yv, lmod, ldiv), ...);

  // D-layout (proven): lane holds D[colidx = mt*16+ldiv*4+j][w = nt*16+lmod]
  // colidx -> e = (ldiv*4+j)&7, r = 2*mt + (ldiv>>1); last tile valid iff ldiv<2
  const int ebase = (ldiv&1)*4;
  const int rofs  = ldiv>>1;
  #pragma unroll
  for(int mt=0; mt<MT; ++mt){
    const bool partial = (mt == MT-1);     // D3 odd -> last tile always half
    const int r = 2*mt + rofs;
    if(!partial || ldiv < 2){
      #pragma unroll
      for(int nt=0;nt<4;++nt)
        #pragma unroll
        for(int j=0;j<4;++j)
          ost[(ebase+j)*STRIDE + (nt*16+lmod)*D3 + r] = acc[mt*4+nt][j];
    }
  }
  __syncthreads();   // ost visible + bounds store concurrency (R12 lesson)

  // coalesced copy-out: 8 lanes per edge, float4 => full 128B lines only
  const int es2 = lane>>3, oct2 = lane&7;
  #pragma unroll
  for(int c=0;c<LEN/32;++c){
    *(float4*)(outb + (long)es2*576 + KOFF + c*32 + oct2*4) =
      *(const float4*)(ost + es2*STRIDE + c*32 + oct2*4);
  }
  __syncthreads();   // ost free for next k-group
}

// split k-group (k2): two 32-col halves through a small ost
template<int KOFF, int D3, int... Is>
__device__ __forceinline__ void kgroup_split(const uint16_t* __restrict__ wt, const char* xsw,
                                             const float* yv, float* __restrict__ outb,
                                             float* __restrict__ ost, int lane,
                                             int lmod, int ldiv)
{
  constexpr int MT     = (D3+1)/2;
  constexpr int LENH   = 32*D3;        // floats per edge per half
  constexpr int STRIDE = LENH + 4;     // == 4 mod 32: conflict-free
  f32x4 acc[MT*4];
  #pragma unroll
  for(int i=0;i<MT*4;++i) acc[i] = (f32x4){0.f,0.f,0.f,0.f};

  (do_instr<Is>(acc, wt, xsw, yv, lmod, ldiv), ...);

  const int ebase = (ldiv&1)*4;
  const int rofs  = ldiv>>1;
  const int es2 = lane>>3, oct2 = lane&7;

  #pragma unroll
  for(int h=0; h<2; ++h){
    // scatter nt ∈ {2h, 2h+1} into ost[e*STRIDE + (ntl*16+lmod)*D3 + r]
    #pragma unroll
    for(int mt=0; mt<MT; ++mt){
      const bool partial = (mt == MT-1);   // D3 odd -> last tile always half
      const int r = 2*mt + rofs;
      if(!partial || ldiv < 2){
        #pragma unroll
        for(int ntl=0; ntl<2; ++ntl)
          #pragma unroll
          for(int j=0;j<4;++j)
            ost[(ebase+j)*STRIDE + (ntl*16+lmod)*D3 + r] = acc[mt*4 + h*2+ntl][j];
      }
    }
    __syncthreads();   // ost visible + store-concurrency bound

    // coalesced copy-out: 8 lanes/edge, float4 -> full 128B lines only
    #pragma unroll
    for(int c=0;c<LENH/32;++c){
      *(float4*)(outb + (long)es2*576 + KOFF + h*LENH + c*32 + oct2*4) =
        *(const float4*)(ost + es2*STRIDE + c*32 + oct2*4);
    }
    __syncthreads();   // ost free for next half / next kgroup
  }
}

// ---------------- main kernel: ONE wave per block, ITER octets ----------------
__global__ __launch_bounds__(64,2) void tp_main(const float* __restrict__ x,
                                                const float* __restrict__ y,
                                                const uint16_t* __restrict__ wt,
                                                float* __restrict__ out)
{
  __shared__ char  xlds[9216]  __attribute__((aligned(16)));
  __shared__ float ost[1568]   __attribute__((aligned(16)));   // 8*(192+4) floats
  const int lane = threadIdx.x & 63;
  const int lmod = lane&15, ldiv = lane>>4;
  const int es = lane>>3, oct = lane&7, e7 = lane&7;
  char* xsw = xlds;

  #pragma unroll 1
  for(int it=0; it<ITER; ++it){
    const long nE = ((long)blockIdx.x*ITER + it)*NE_W;

    // per-lane y (compute edge e7)
    float yv[9];
    {
      const float* yp = y + (nE + e7)*9;
      #pragma unroll
      for(int q=0;q<9;++q) yv[q] = yp[q];
    }

    // ---- stage x (8 edges) into LDS: PROVEN register pack + XOR swizzle ----
    {
      const float* xr = x + (nE+es)*576;
      uint32_t xp[9][4];   // xp[pidx][a] = bf16 pair (u=oct*8+2a, u=oct*8+2a+1)

      const float4 a0 = *(const float4*)(xr + oct*8);
      const float4 a1 = *(const float4*)(xr + oct*8 + 4);
      xp[0][0]=pk2c(a0.x,a0.y); xp[0][1]=pk2c(a0.z,a0.w);
      xp[0][2]=pk2c(a1.x,a1.y); xp[0][3]=pk2c(a1.z,a1.w);
      float f1[24];
      {
        const float4* p1 = (const float4*)(xr + 64 + oct*24);
        #pragma unroll
        for(int i=0;i<6;++i){ float4 v=p1[i]; f1[4*i]=v.x; f1[4*i+1]=v.y; f1[4*i+2]=v.z; f1[4*i+3]=v.w; }
      }
      #pragma unroll
      for(int p=0;p<3;++p)
        #pragma unroll
        for(int a=0;a<4;++a) xp[1+p][a] = pk2c(f1[(2*a)*3+p], f1[(2*a+1)*3+p]);
      float f2[40];
      {
        const float4* p2 = (const float4*)(xr + 256 + oct*40);
        #pragma unroll
        for(int i=0;i<10;++i){ float4 v=p2[i]; f2[4*i]=v.x; f2[4*i+1]=v.y; f2[4*i+2]=v.z; f2[4*i+3]=v.w; }
      }
      #pragma unroll
      for(int p=0;p<5;++p)
        #pragma unroll
        for(int a=0;a<4;++a) xp[4+p][a] = pk2c(f2[(2*a)*5+p], f2[(2*a+1)*5+p]);

      // 9 ds_write_b128: row rho = es*9+pidx, chunk oct at position oct^(rho&7)
      #pragma unroll
      for(int pidx=0;pidx<9;++pidx){
        const int rho = es*9 + pidx;
        *(u32x4*)(xsw + rho*128 + ((oct ^ (rho&7))<<4)) = *(const u32x4*)&xp[pidx][0];
      }
    }

    // fence: staging ds_writes complete+ordered before compute ds_reads
    __syncthreads();

    float* outb = out + nE*576;
    // k0 (l3=0, koff 0):   I = 0:(000) 4:(110) 9:(220)
    kgroup<0,   1, 0,4,9   >(wt, xsw, yv, outb, ost, lane, lmod, ldiv);
    // k1 (l3=1, koff 64):  I = 1:(011) 3:(101) 6:(121) 8:(211)
    kgroup<64,  3, 1,3,6,8 >(wt, xsw, yv, outb, ost, lane, lmod, ldiv);
    // k2 (l3=2, koff 256): I = 2:(022) 5:(112) 7:(202) 10:(222)  [h-split]
    kgroup_split<256, 5, 2,5,7,10>(wt, xsw, yv, outb, ost, lane, lmod, ldiv);
    // (kgroup_split ends with __syncthreads -> next iter's staging is ordered)
  }
}

// ---------------- launch ----------------
extern "C" void kernel_launch(void* const* d_in, const int* in_sizes, int n_in,
                              void* d_out, int out_size, void* d_ws, size_t ws_size,
                              hipStream_t stream)
{
  const float* x = (const float*)d_in[0];
  const float* y = (const float*)d_in[1];
  const float* w = (const float*)d_in[2];
  uint16_t* wt = (uint16_t*)d_ws;                 // 11*4096*2 = 90112 B
  prep_w<<<176, 256, 0, stream>>>(w, wt);
  tp_main<<<NBLK, 64, 0, stream>>>(x, y, wt, (float*)d_out);
}

// Round 16
// 142.364 us; speedup vs baseline: 1.5560x; 1.5560x over previous
//
#include <hip/hip_runtime.h>
#include <hip/hip_bf16.h>
#include <stdint.h>

// ---------------------------------------------------------------------------
// OEQTensorProduct: x[N,576] (64x{0e,1o,2e}) (x) y[N,9] ({0e,1o,2e}) -> out[N,576]
// 1-wave blocks, NE_W=16 edges per wave, grid 6250.
// R16: 16-edge tiles. col = r*16+e -> every MFMA tile is ONE r: no partial
// tiles; B-loads / xf-reads / barriers / M per EDGE halve; MFMA/edge -24%.
// Mappings (derived from proven 8-edge conventions):
//   A-frag: lane holds A[i=lmod][k=ks*32+ldiv*8+i'] = z[u][e=lmod, r=rt]
//   D-frag: lane holds D[e=ldiv*4+j][w=nt*16+lmod] for tile rt
// Store path (R7/R12-proven): scatter acc->ost (stride==4 mod 32), barrier,
// float4 coalesced copy-out, barrier. R13's PINNED B-prefetch chain kept.
// ---------------------------------------------------------------------------

#define NEDGES 100000
#define NE_W   16                   // edges per wave(block)
#define NBLK   (NEDGES/NE_W)        // 6250 one-wave blocks

typedef short    short8 __attribute__((ext_vector_type(8)));
typedef float    f32x4  __attribute__((ext_vector_type(4)));
typedef uint32_t u32x4  __attribute__((ext_vector_type(4)));

// ---------------- compile-time Wigner-3j (real basis) tables ----------------
constexpr int L1A[11] = {0,0,0,1,1,1,1,2,2,2,2};
constexpr int L2A[11] = {0,1,2,0,1,1,2,0,1,2,2};
constexpr int L3A[11] = {0,1,2,1,0,2,1,2,1,0,2};

constexpr double cfact(int n){ double r=1.0; for(int i=2;i<=n;++i) r*=(double)i; return r; }
constexpr double csqrt(double x){ if(x<=0.0) return 0.0; double g = x>1.0?x:1.0;
                                 for(int i=0;i<80;++i) g=0.5*(g+x/g); return g; }
constexpr int imax2(int a,int b){return a>b?a:b;}
constexpr int imin2(int a,int b){return a<b?a:b;}

constexpr double su2_cg(int j1,int j2,int j3,int m1,int m2,int m3){
  if(m3 != m1+m2) return 0.0;
  int vmin = imax2(imax2(-j1+j2+m3, -j1+m1), 0);
  int vmax = imin2(imin2(j2+j3+m1, j3-j1+j2), j3+m3);
  double c = csqrt((double)(2*j3+1)*cfact(j3+j1-j2)*cfact(j3-j1+j2)*cfact(j1+j2-j3)
                   *cfact(j3+m3)*cfact(j3-m3)
                   /(cfact(j1+j2+j3+1)*cfact(j1-m1)*cfact(j1+m1)*cfact(j2-m2)*cfact(j2+m2)));
  double s=0.0;
  for(int v=vmin; v<=vmax; ++v){
    double sg = ((v+j2+m2)&1)? -1.0 : 1.0;
    s += sg*cfact(j2+j3+m1-v)*cfact(j1-m1+v)
         /(cfact(v)*cfact(j3-j1+j2-v)*cfact(j3+m3-v)*cfact(j1-j2-m3+v));
  }
  return c*s;
}

struct Cplx{ double re, im; };
struct Q55 { Cplx q[5][5]; };

constexpr Q55 change_basis(int l){
  Q55 Q{};
  const double is2 = 1.0/csqrt(2.0);
  for(int m=-l;m<0;++m){
    Q.q[l+m][l-m].re =  is2;
    Q.q[l+m][l+m].im = -is2;
  }
  Q.q[l][l].re = 1.0;
  for(int m=1;m<=l;++m){
    double s = (m&1)? -1.0 : 1.0;
    Q.q[l+m][l+m].re = s*is2;
    Q.q[l+m][l-m].im = s*is2;
  }
  for(int i=0;i<5;++i) for(int j=0;j<5;++j){
    double re=Q.q[i][j].re, im=Q.q[i][j].im;
    if(l==1){ Q.q[i][j].re = im;  Q.q[i][j].im = -re; }
    else if(l==2){ Q.q[i][j].re = -re; Q.q[i][j].im = -im; }
  }
  return Q;
}

struct Tbl {
  double C[11][5][5][5];   // [I][p][q][r]
  double alpha[11];
};

constexpr Tbl build_tbl(){
  Tbl T{};
  for(int I=0;I<11;++I){
    const int l1=L1A[I], l2=L2A[I], l3=L3A[I];
    const int D1=2*l1+1, D2=2*l2+1, D3=2*l3+1;
    double cg[5][5][5]{};
    for(int a=0;a<D1;++a)for(int b=0;b<D2;++b){
      int m3 = (a-l1)+(b-l2);
      if(m3>=-l3 && m3<=l3) cg[a][b][l3+m3] = su2_cg(l1,l2,l3,a-l1,b-l2,m3);
    }
    Q55 q1 = change_basis(l1), q2 = change_basis(l2), q3 = change_basis(l3);
    Cplx T1[5][5][5]{};
    for(int i=0;i<D1;++i)for(int b=0;b<D2;++b)for(int c=0;c<D3;++c){
      double re=0,im=0;
      for(int a=0;a<D1;++a){ re += q1.q[a][i].re*cg[a][b][c]; im += q1.q[a][i].im*cg[a][b][c]; }
      T1[i][b][c].re=re; T1[i][b][c].im=im;
    }
    Cplx T2[5][5][5]{};
    for(int i=0;i<D1;++i)for(int j=0;j<D2;++j)for(int c=0;c<D3;++c){
      double re=0,im=0;
      for(int b=0;b<D2;++b){
        double qr=q2.q[b][j].re, qi=q2.q[b][j].im;
        re += qr*T1[i][b][c].re - qi*T1[i][b][c].im;
        im += qr*T1[i][b][c].im + qi*T1[i][b][c].re;
      }
      T2[i][j][c].re=re; T2[i][j][c].im=im;
    }
    double nrm2 = 0.0;
    for(int i=0;i<D1;++i)for(int j=0;j<D2;++j)for(int k=0;k<D3;++k){
      double re=0;
      for(int c=0;c<D3;++c){
        double qr=q3.q[c][k].re, qi=-q3.q[c][k].im;   // conj
        re += qr*T2[i][j][c].re - qi*T2[i][j][c].im;
      }
      T.C[I][i][j][k] = re; nrm2 += re*re;
    }
    double nrm = csqrt(nrm2);
    if(nrm > 0.0)
      for(int i=0;i<D1;++i)for(int j=0;j<D2;++j)for(int k=0;k<D3;++k) T.C[I][i][j][k] /= nrm;
    const int fan = (l3==0)?192:256;
    T.alpha[I] = csqrt((double)(2*l3+1)/(double)fan);
  }
  return T;
}

constexpr Tbl TBL = build_tbl();

__device__ const float c_alpha[11] = {
  (float)TBL.alpha[0],(float)TBL.alpha[1],(float)TBL.alpha[2],(float)TBL.alpha[3],
  (float)TBL.alpha[4],(float)TBL.alpha[5],(float)TBL.alpha[6],(float)TBL.alpha[7],
  (float)TBL.alpha[8],(float)TBL.alpha[9],(float)TBL.alpha[10]
};

// ---------------- device helpers ----------------
__device__ __forceinline__ uint16_t f2bf(float f){      // fp32 -> bf16 RNE
  uint32_t u = __float_as_uint(f);
  return (uint16_t)((u + 0x7fffu + ((u>>16)&1u)) >> 16);
}
// compiler-recognized packed bf16 convert (emits v_cvt_pk_bf16_f32, RNE)
__device__ __forceinline__ uint32_t pk2c(float a, float b){
  __hip_bfloat162 h = __float22bfloat162_rn(float2{a,b});
  uint32_t r; __builtin_memcpy(&r, &h, 4); return r;
}

// ---------------- W pre-transform: Wt[I][w][u] = bf16(alpha_I * W[I][u][w]) ----
__global__ __launch_bounds__(256) void prep_w(const float* __restrict__ w,
                                              uint16_t* __restrict__ wt){
  int tid = blockIdx.x*256 + threadIdx.x;
  if(tid >= 11*4096) return;
  int I = tid >> 12;
  int rem = tid & 4095;
  int wo = rem >> 6, u = rem & 63;
  wt[tid] = f2bf(c_alpha[I] * w[(I<<12) + (u<<6) + wo]);
}

// ---------------------------------------------------------------------------
// xs LDS layout (18432 B): row rho = e*9 + pidx (e<16), 64 u's x 2B = 128 B;
// 16-B chunk s (u = s*8..s*8+7) stored at position s ^ (rho&7).
// ost LDS (3136 floats = 12544 B): per-kgroup tile, per-edge stride LEN+4
// (k0: 68, k1: 196) or, for k2 h-split, 164. All strides == 4 mod 32.
// ---------------------------------------------------------------------------

// B-fragment load: 8x global_load_dwordx4 from wt (lmod/ldiv-dependent only)
template<int I>
__device__ __forceinline__ void load_B(short8 B[2][4], const uint16_t* __restrict__ wt,
                                       int lmod, int ldiv){
  #pragma unroll
  for(int ks=0;ks<2;++ks)
    #pragma unroll
    for(int nt=0;nt<4;++nt)
      B[ks][nt] = *(const short8*)(wt + (I*64 + nt*16 + lmod)*64 + ks*32 + ldiv*8);
}

// one instruction with preloaded B: accumulate into acc[rt*4+nt]
// A-frag: lane (lmod,ldiv) computes z[u=ks*32+ldiv*8+i][e=lmod, r=rt]
template<int I>
__device__ __forceinline__ void do_instr_pre(f32x4* acc, const short8 B[2][4],
                                             const char* xsw, const float* yv,
                                             int lmod, int ldiv)
{
  constexpr int l1=L1A[I], l2=L2A[I], l3=L3A[I];
  constexpr int D1=2*l1+1, D2=2*l2+1, D3=2*l3+1;
  constexpr int PB=(l1==0)?0:((l1==1)?1:4);
  constexpr int QB=(l2==0)?0:((l2==1)?1:4);

  // M[p][r] = sum_q C[p][q][r] * y[q]  (compile-time C, lane-local y of edge lmod)
  float M[D1][D3];
  #pragma unroll
  for(int p=0;p<D1;++p)
    #pragma unroll
    for(int r=0;r<D3;++r){
      float m=0.f;
      #pragma unroll
      for(int q=0;q<D2;++q){
        const float cc = (float)TBL.C[I][p][q][r];
        if(cc != 0.0f) m = fmaf(cc, yv[QB+q], m);
      }
      M[p][r]=m;
    }

  #pragma unroll
  for(int ks=0;ks<2;++ks){
    // hoisted LDS reads + unpack: x[e=lmod][u-chunk ks*4+ldiv][p]
    float xf[D1][8];
    #pragma unroll
    for(int p=0;p<D1;++p){
      const int rho  = lmod*9 + PB + p;
      const int addr = rho*128 + (((ks*4+ldiv) ^ (rho&7))<<4);
      const u32x4 xv = *(const u32x4*)(xsw + addr);
      #pragma unroll
      for(int k=0;k<4;++k){
        xf[p][2*k]   = __uint_as_float(xv[k]<<16);
        xf[p][2*k+1] = __uint_as_float(xv[k]&0xffff0000u);
      }
    }
    #pragma unroll
    for(int rt=0;rt<D3;++rt){
      float zf[8];
      #pragma unroll
      for(int i=0;i<8;++i) zf[i]=0.f;
      #pragma unroll
      for(int p=0;p<D1;++p)
        #pragma unroll
        for(int i=0;i<8;++i) zf[i] = fmaf(M[p][rt], xf[p][i], zf[i]);
      u32x4 av = { pk2c(zf[0],zf[1]), pk2c(zf[2],zf[3]),
                   pk2c(zf[4],zf[5]), pk2c(zf[6],zf[7]) };
      const short8 A = *(const short8*)&av;
      #pragma unroll
      for(int nt=0;nt<4;++nt)
        acc[rt*4+nt] = __builtin_amdgcn_mfma_f32_16x16x32_bf16(A, B[ks][nt], acc[rt*4+nt], 0,0,0);
    }
  }
}

// pinned prefetch chain (R13-proven): issue next-B loads, pin, consume current
template<int I>
__device__ __forceinline__ void chain1(f32x4* acc, const short8 B[2][4],
                                       const uint16_t* __restrict__ wt,
                                       const char* xsw, const float* yv,
                                       int lmod, int ldiv){
  do_instr_pre<I>(acc, B, xsw, yv, lmod, ldiv);
}

template<int I, int J, int... Rest>
__device__ __forceinline__ void chain1(f32x4* acc, const short8 B[2][4],
                                       const uint16_t* __restrict__ wt,
                                       const char* xsw, const float* yv,
                                       int lmod, int ldiv){
  short8 Bn[2][4];
  load_B<J>(Bn, wt, lmod, ldiv);                 // issue next-B loads NOW
  __builtin_amdgcn_sched_barrier(0);             // pin: no sinking past here
  do_instr_pre<I>(acc, B, xsw, yv, lmod, ldiv);  // compute hides them
  chain1<J, Rest...>(acc, Bn, wt, xsw, yv, lmod, ldiv);
}

// full k-group (k0, k1): chain, scatter to ost, barrier, float4 copy-out
// D: lane holds D[e = ldiv*4+j][w = nt*16+lmod] for tile rt (no partial tiles)
template<int KOFF, int D3, int IF, int... Is>
__device__ __forceinline__ void kgroup(const uint16_t* __restrict__ wt, const char* xsw,
                                       const float* yv, float* __restrict__ outb,
                                       float* __restrict__ ost, int lane,
                                       int lmod, int ldiv)
{
  constexpr int LEN    = 64*D3;        // floats per edge in this k-group
  constexpr int STRIDE = LEN + 4;      // == 4 mod 32: conflict-free
  f32x4 acc[D3*4];
  #pragma unroll
  for(int i=0;i<D3*4;++i) acc[i] = (f32x4){0.f,0.f,0.f,0.f};

  short8 B0[2][4];
  load_B<IF>(B0, wt, lmod, ldiv);
  __builtin_amdgcn_sched_barrier(0);
  chain1<IF, Is...>(acc, B0, wt, xsw, yv, lmod, ldiv);

  #pragma unroll
  for(int rt=0; rt<D3; ++rt)
    #pragma unroll
    for(int nt=0;nt<4;++nt)
      #pragma unroll
      for(int j=0;j<4;++j)
        ost[(ldiv*4+j)*STRIDE + (nt*16+lmod)*D3 + rt] = acc[rt*4+nt][j];
  __syncthreads();   // ost visible + bounds store concurrency (R12 lesson)

  // coalesced copy-out: 4 lanes per edge, float4 -> 64B contiguous per edge
  const int es2 = lane>>2, oct2 = lane&3;
  #pragma unroll
  for(int c=0;c<LEN/16;++c){
    *(float4*)(outb + (long)es2*576 + KOFF + c*16 + oct2*4) =
      *(const float4*)(ost + es2*STRIDE + c*16 + oct2*4);
  }
  __syncthreads();   // ost free for next k-group
}

// split k-group (k2): two 32-col (w) halves through a smaller ost
template<int KOFF, int D3, int IF, int... Is>
__device__ __forceinline__ void kgroup_split(const uint16_t* __restrict__ wt, const char* xsw,
                                             const float* yv, float* __restrict__ outb,
                                             float* __restrict__ ost, int lane,
                                             int lmod, int ldiv)
{
  constexpr int LENH   = 32*D3;        // floats per edge per half (160)
  constexpr int STRIDE = LENH + 4;     // 164 == 4 mod 32
  f32x4 acc[D3*4];
  #pragma unroll
  for(int i=0;i<D3*4;++i) acc[i] = (f32x4){0.f,0.f,0.f,0.f};

  short8 B0[2][4];
  load_B<IF>(B0, wt, lmod, ldiv);
  __builtin_amdgcn_sched_barrier(0);
  chain1<IF, Is...>(acc, B0, wt, xsw, yv, lmod, ldiv);

  const int es2 = lane>>2, oct2 = lane&3;
  #pragma unroll
  for(int h=0; h<2; ++h){
    #pragma unroll
    for(int rt=0; rt<D3; ++rt)
      #pragma unroll
      for(int ntl=0; ntl<2; ++ntl)
        #pragma unroll
        for(int j=0;j<4;++j)
          ost[(ldiv*4+j)*STRIDE + (ntl*16+lmod)*D3 + rt] = acc[rt*4 + h*2+ntl][j];
    __syncthreads();   // ost visible + store-concurrency bound

    #pragma unroll
    for(int c=0;c<LENH/16;++c){
      *(float4*)(outb + (long)es2*576 + KOFF + h*LENH + c*16 + oct2*4) =
        *(const float4*)(ost + es2*STRIDE + c*16 + oct2*4);
    }
    __syncthreads();   // ost free for next half / next kgroup
  }
}

// ---------------- main kernel: ONE wave per block, 16 edges ----------------
__global__ __launch_bounds__(64,2) void tp_main(const float* __restrict__ x,
                                                const float* __restrict__ y,
                                                const uint16_t* __restrict__ wt,
                                                float* __restrict__ out)
{
  __shared__ char  xlds[18432] __attribute__((aligned(16)));
  __shared__ float ost[3136]   __attribute__((aligned(16)));   // 16*(192+4)
  const int lane = threadIdx.x & 63;
  const int lmod = lane&15, ldiv = lane>>4;
  const long nE = (long)blockIdx.x*NE_W;
  char* xsw = xlds;

  // per-lane y: compute edge e = lmod (16 edges)
  float yv[9];
  {
    const float* yp = y + (nE + lmod)*9;
    #pragma unroll
    for(int q=0;q<9;++q) yv[q] = yp[q];
  }

  // ---- stage x (16 edges): 4 lanes/edge, 16 u's/lane; proven pack pattern ----
  {
    const int es = lane>>2, q4 = lane&3;          // edge, u-quarter (u=q4*16..+16)
    const float* xr = x + (nE+es)*576;

    // group0 (l=0, pidx 0): 16 floats at xr + q4*16
    {
      float f0[16];
      #pragma unroll
      for(int i=0;i<4;++i){ float4 v = *(const float4*)(xr + q4*16 + 4*i);
        f0[4*i]=v.x; f0[4*i+1]=v.y; f0[4*i+2]=v.z; f0[4*i+3]=v.w; }
      uint32_t xp[8];
      #pragma unroll
      for(int a=0;a<8;++a) xp[a] = pk2c(f0[2*a], f0[2*a+1]);
      const int rho = es*9;
      char* base = xsw + rho*128;
      *(u32x4*)(base + (((2*q4  ) ^ (rho&7))<<4)) = *(const u32x4*)&xp[0];
      *(u32x4*)(base + (((2*q4+1) ^ (rho&7))<<4)) = *(const u32x4*)&xp[4];
    }
    // group1 (l=1, pidx 1..3): 48 floats at xr + 64 + q4*48; elem (m,p) at m*3+p
    {
      float f1[48];
      #pragma unroll
      for(int i=0;i<12;++i){ float4 v = *(const float4*)(xr + 64 + q4*48 + 4*i);
        f1[4*i]=v.x; f1[4*i+1]=v.y; f1[4*i+2]=v.z; f1[4*i+3]=v.w; }
      #pragma unroll
      for(int p=0;p<3;++p){
        uint32_t xp[8];
        #pragma unroll
        for(int a=0;a<8;++a) xp[a] = pk2c(f1[(2*a)*3+p], f1[(2*a+1)*3+p]);
        const int rho = es*9 + 1 + p;
        char* base = xsw + rho*128;
        *(u32x4*)(base + (((2*q4  ) ^ (rho&7))<<4)) = *(const u32x4*)&xp[0];
        *(u32x4*)(base + (((2*q4+1) ^ (rho&7))<<4)) = *(const u32x4*)&xp[4];
      }
    }
    // group2 (l=2, pidx 4..8): 80 floats at xr + 256 + q4*80; elem (m,p) at m*5+p
    {
      float f2[80];
      #pragma unroll
      for(int i=0;i<20;++i){ float4 v = *(const float4*)(xr + 256 + q4*80 + 4*i);
        f2[4*i]=v.x; f2[4*i+1]=v.y; f2[4*i+2]=v.z; f2[4*i+3]=v.w; }
      #pragma unroll
      for(int p=0;p<5;++p){
        uint32_t xp[8];
        #pragma unroll
        for(int a=0;a<8;++a) xp[a] = pk2c(f2[(2*a)*5+p], f2[(2*a+1)*5+p]);
        const int rho = es*9 + 4 + p;
        char* base = xsw + rho*128;
        *(u32x4*)(base + (((2*q4  ) ^ (rho&7))<<4)) = *(const u32x4*)&xp[0];
        *(u32x4*)(base + (((2*q4+1) ^ (rho&7))<<4)) = *(const u32x4*)&xp[4];
      }
    }
  }

  // fence: staging ds_writes complete+ordered before compute ds_reads
  __syncthreads();

  float* outb = out + nE*576;
  // k0 (l3=0, koff 0):   I = 0:(000) 4:(110) 9:(220)
  kgroup<0,   1, 0,4,9   >(wt, xsw, yv, outb, ost, lane, lmod, ldiv);
  // k1 (l3=1, koff 64):  I = 1:(011) 3:(101) 6:(121) 8:(211)
  kgroup<64,  3, 1,3,6,8 >(wt, xsw, yv, outb, ost, lane, lmod, ldiv);
  // k2 (l3=2, koff 256): I = 2:(022) 5:(112) 7:(202) 10:(222)  [h-split]
  kgroup_split<256, 5, 2,5,7,10>(wt, xsw, yv, outb, ost, lane, lmod, ldiv);
}

// ---------------- launch ----------------
extern "C" void kernel_launch(void* const* d_in, const int* in_sizes, int n_in,
                              void* d_out, int out_size, void* d_ws, size_t ws_size,
                              hipStream_t stream)
{
  const float* x = (const float*)d_in[0];
  const float* y = (const float*)d_in[1];
  const float* w = (const float*)d_in[2];
  uint16_t* wt = (uint16_t*)d_ws;                 // 11*4096*2 = 90112 B
  prep_w<<<176, 256, 0, stream>>>(w, wt);
  tp_main<<<NBLK, 64, 0, stream>>>(x, y, wt, (float*)d_out);
}

// Round 17
// 130.278 us; speedup vs baseline: 1.7004x; 1.0928x over previous
//
#include <hip/hip_runtime.h>
#include <hip/hip_bf16.h>
#include <stdint.h>

// ---------------------------------------------------------------------------
// OEQTensorProduct: x[N,576] (64x{0e,1o,2e}) (x) y[N,9] ({0e,1o,2e}) -> out[N,576]
// R17: 2-WAVE blocks (128 thr) sharing one 16-edge x-tile in LDS.
//   wave0: k0 (full ost, stride 68) + k1 (h-split, stride 100)
//   wave1: k2 (q-split, stride 84)
// LDS 30208 B => 5 blocks/CU x 2 waves = 10 waves/CU (2x R16's density).
// Inside divergent kgroup paths: per-wave fence `s_waitcnt vmcnt(0)
// lgkmcnt(0)` (same semantics as R7's __syncthreads for ONE wave: drains
// stores -> R12-proven concurrency bound; orders ost ds ops) -- no barrier,
// no cross-wave coupling. One real __syncthreads after staging only.
// Compute core = R16 (142.4us, proven @2.4e-4): 16-edge MFMA mapping,
// pinned B-prefetch chain, pk2c packing.
// ---------------------------------------------------------------------------

#define NEDGES 100000
#define NE_W   16                   // edges per block
#define NBLK   (NEDGES/NE_W)        // 6250 two-wave blocks

typedef short    short8 __attribute__((ext_vector_type(8)));
typedef float    f32x4  __attribute__((ext_vector_type(4)));
typedef uint32_t u32x4  __attribute__((ext_vector_type(4)));

// ---------------- compile-time Wigner-3j (real basis) tables ----------------
constexpr int L1A[11] = {0,0,0,1,1,1,1,2,2,2,2};
constexpr int L2A[11] = {0,1,2,0,1,1,2,0,1,2,2};
constexpr int L3A[11] = {0,1,2,1,0,2,1,2,1,0,2};

constexpr double cfact(int n){ double r=1.0; for(int i=2;i<=n;++i) r*=(double)i; return r; }
constexpr double csqrt(double x){ if(x<=0.0) return 0.0; double g = x>1.0?x:1.0;
                                 for(int i=0;i<80;++i) g=0.5*(g+x/g); return g; }
constexpr int imax2(int a,int b){return a>b?a:b;}
constexpr int imin2(int a,int b){return a<b?a:b;}

constexpr double su2_cg(int j1,int j2,int j3,int m1,int m2,int m3){
  if(m3 != m1+m2) return 0.0;
  int vmin = imax2(imax2(-j1+j2+m3, -j1+m1), 0);
  int vmax = imin2(imin2(j2+j3+m1, j3-j1+j2), j3+m3);
  double c = csqrt((double)(2*j3+1)*cfact(j3+j1-j2)*cfact(j3-j1+j2)*cfact(j1+j2-j3)
                   *cfact(j3+m3)*cfact(j3-m3)
                   /(cfact(j1+j2+j3+1)*cfact(j1-m1)*cfact(j1+m1)*cfact(j2-m2)*cfact(j2+m2)));
  double s=0.0;
  for(int v=vmin; v<=vmax; ++v){
    double sg = ((v+j2+m2)&1)? -1.0 : 1.0;
    s += sg*cfact(j2+j3+m1-v)*cfact(j1-m1+v)
         /(cfact(v)*cfact(j3-j1+j2-v)*cfact(j3+m3-v)*cfact(j1-j2-m3+v));
  }
  return c*s;
}

struct Cplx{ double re, im; };
struct Q55 { Cplx q[5][5]; };

constexpr Q55 change_basis(int l){
  Q55 Q{};
  const double is2 = 1.0/csqrt(2.0);
  for(int m=-l;m<0;++m){
    Q.q[l+m][l-m].re =  is2;
    Q.q[l+m][l+m].im = -is2;
  }
  Q.q[l][l].re = 1.0;
  for(int m=1;m<=l;++m){
    double s = (m&1)? -1.0 : 1.0;
    Q.q[l+m][l+m].re = s*is2;
    Q.q[l+m][l-m].im = s*is2;
  }
  for(int i=0;i<5;++i) for(int j=0;j<5;++j){
    double re=Q.q[i][j].re, im=Q.q[i][j].im;
    if(l==1){ Q.q[i][j].re = im;  Q.q[i][j].im = -re; }
    else if(l==2){ Q.q[i][j].re = -re; Q.q[i][j].im = -im; }
  }
  return Q;
}

struct Tbl {
  double C[11][5][5][5];   // [I][p][q][r]
  double alpha[11];
};

constexpr Tbl build_tbl(){
  Tbl T{};
  for(int I=0;I<11;++I){
    const int l1=L1A[I], l2=L2A[I], l3=L3A[I];
    const int D1=2*l1+1, D2=2*l2+1, D3=2*l3+1;
    double cg[5][5][5]{};
    for(int a=0;a<D1;++a)for(int b=0;b<D2;++b){
      int m3 = (a-l1)+(b-l2);
      if(m3>=-l3 && m3<=l3) cg[a][b][l3+m3] = su2_cg(l1,l2,l3,a-l1,b-l2,m3);
    }
    Q55 q1 = change_basis(l1), q2 = change_basis(l2), q3 = change_basis(l3);
    Cplx T1[5][5][5]{};
    for(int i=0;i<D1;++i)for(int b=0;b<D2;++b)for(int c=0;c<D3;++c){
      double re=0,im=0;
      for(int a=0;a<D1;++a){ re += q1.q[a][i].re*cg[a][b][c]; im += q1.q[a][i].im*cg[a][b][c]; }
      T1[i][b][c].re=re; T1[i][b][c].im=im;
    }
    Cplx T2[5][5][5]{};
    for(int i=0;i<D1;++i)for(int j=0;j<D2;++j)for(int c=0;c<D3;++c){
      double re=0,im=0;
      for(int b=0;b<D2;++b){
        double qr=q2.q[b][j].re, qi=q2.q[b][j].im;
        re += qr*T1[i][b][c].re - qi*T1[i][b][c].im;
        im += qr*T1[i][b][c].im + qi*T1[i][b][c].re;
      }
      T2[i][j][c].re=re; T2[i][j][c].im=im;
    }
    double nrm2 = 0.0;
    for(int i=0;i<D1;++i)for(int j=0;j<D2;++j)for(int k=0;k<D3;++k){
      double re=0;
      for(int c=0;c<D3;++c){
        double qr=q3.q[c][k].re, qi=-q3.q[c][k].im;   // conj
        re += qr*T2[i][j][c].re - qi*T2[i][j][c].im;
      }
      T.C[I][i][j][k] = re; nrm2 += re*re;
    }
    double nrm = csqrt(nrm2);
    if(nrm > 0.0)
      for(int i=0;i<D1;++i)for(int j=0;j<D2;++j)for(int k=0;k<D3;++k) T.C[I][i][j][k] /= nrm;
    const int fan = (l3==0)?192:256;
    T.alpha[I] = csqrt((double)(2*l3+1)/(double)fan);
  }
  return T;
}

constexpr Tbl TBL = build_tbl();

__device__ const float c_alpha[11] = {
  (float)TBL.alpha[0],(float)TBL.alpha[1],(float)TBL.alpha[2],(float)TBL.alpha[3],
  (float)TBL.alpha[4],(float)TBL.alpha[5],(float)TBL.alpha[6],(float)TBL.alpha[7],
  (float)TBL.alpha[8],(float)TBL.alpha[9],(float)TBL.alpha[10]
};

// ---------------- device helpers ----------------
__device__ __forceinline__ uint16_t f2bf(float f){      // fp32 -> bf16 RNE
  uint32_t u = __float_as_uint(f);
  return (uint16_t)((u + 0x7fffu + ((u>>16)&1u)) >> 16);
}
// compiler-recognized packed bf16 convert (emits v_cvt_pk_bf16_f32, RNE)
__device__ __forceinline__ uint32_t pk2c(float a, float b){
  __hip_bfloat162 h = __float22bfloat162_rn(float2{a,b});
  uint32_t r; __builtin_memcpy(&r, &h, 4); return r;
}
// per-wave fence: exactly __syncthreads' waitcnt semantics for ONE wave
// (drains this wave's global stores -> R12's store-concurrency bound; orders
// ds writes vs reads) without the inter-wave s_barrier.
__device__ __forceinline__ void wave_fence(){
  asm volatile("s_waitcnt vmcnt(0) lgkmcnt(0)" ::: "memory");
  __builtin_amdgcn_sched_barrier(0);
}

// ---------------- W pre-transform: Wt[I][w][u] = bf16(alpha_I * W[I][u][w]) ----
__global__ __launch_bounds__(256) void prep_w(const float* __restrict__ w,
                                              uint16_t* __restrict__ wt){
  int tid = blockIdx.x*256 + threadIdx.x;
  if(tid >= 11*4096) return;
  int I = tid >> 12;
  int rem = tid & 4095;
  int wo = rem >> 6, u = rem & 63;
  wt[tid] = f2bf(c_alpha[I] * w[(I<<12) + (u<<6) + wo]);
}

// ---------------------------------------------------------------------------
// xlds (18432 B): row rho = e*9 + pidx (e<16), 64 u's x 2B = 128 B;
// 16-B chunk s (u = s*8..s*8+7) stored at position s ^ (rho&7).
// ost0 (1600 fl = 6400 B, wave0): k0 stride 68 / k1 h-split stride 100.
// ost1 (1344 fl = 5376 B, wave1): k2 q-split stride 84. All == 4 mod 32.
// ---------------------------------------------------------------------------

// B-fragment load: 8x global_load_dwordx4 from wt
template<int I>
__device__ __forceinline__ void load_B(short8 B[2][4], const uint16_t* __restrict__ wt,
                                       int lmod, int ldiv){
  #pragma unroll
  for(int ks=0;ks<2;++ks)
    #pragma unroll
    for(int nt=0;nt<4;++nt)
      B[ks][nt] = *(const short8*)(wt + (I*64 + nt*16 + lmod)*64 + ks*32 + ldiv*8);
}

// one instruction with preloaded B (16-edge mapping, R16-proven):
// A-frag: lane computes z[u=ks*32+ldiv*8+i][e=lmod, r=rt]; acc[rt*4+nt]
template<int I>
__device__ __forceinline__ void do_instr_pre(f32x4* acc, const short8 B[2][4],
                                             const char* xsw, const float* yv,
                                             int lmod, int ldiv)
{
  constexpr int l1=L1A[I], l2=L2A[I], l3=L3A[I];
  constexpr int D1=2*l1+1, D2=2*l2+1, D3=2*l3+1;
  constexpr int PB=(l1==0)?0:((l1==1)?1:4);
  constexpr int QB=(l2==0)?0:((l2==1)?1:4);

  float M[D1][D3];
  #pragma unroll
  for(int p=0;p<D1;++p)
    #pragma unroll
    for(int r=0;r<D3;++r){
      float m=0.f;
      #pragma unroll
      for(int q=0;q<D2;++q){
        const float cc = (float)TBL.C[I][p][q][r];
        if(cc != 0.0f) m = fmaf(cc, yv[QB+q], m);
      }
      M[p][r]=m;
    }

  #pragma unroll
  for(int ks=0;ks<2;++ks){
    float xf[D1][8];
    #pragma unroll
    for(int p=0;p<D1;++p){
      const int rho  = lmod*9 + PB + p;
      const int addr = rho*128 + (((ks*4+ldiv) ^ (rho&7))<<4);
      const u32x4 xv = *(const u32x4*)(xsw + addr);
      #pragma unroll
      for(int k=0;k<4;++k){
        xf[p][2*k]   = __uint_as_float(xv[k]<<16);
        xf[p][2*k+1] = __uint_as_float(xv[k]&0xffff0000u);
      }
    }
    #pragma unroll
    for(int rt=0;rt<D3;++rt){
      float zf[8];
      #pragma unroll
      for(int i=0;i<8;++i) zf[i]=0.f;
      #pragma unroll
      for(int p=0;p<D1;++p)
        #pragma unroll
        for(int i=0;i<8;++i) zf[i] = fmaf(M[p][rt], xf[p][i], zf[i]);
      u32x4 av = { pk2c(zf[0],zf[1]), pk2c(zf[2],zf[3]),
                   pk2c(zf[4],zf[5]), pk2c(zf[6],zf[7]) };
      const short8 A = *(const short8*)&av;
      #pragma unroll
      for(int nt=0;nt<4;++nt)
        acc[rt*4+nt] = __builtin_amdgcn_mfma_f32_16x16x32_bf16(A, B[ks][nt], acc[rt*4+nt], 0,0,0);
    }
  }
}

// pinned prefetch chain (R13-proven)
template<int I>
__device__ __forceinline__ void chain1(f32x4* acc, const short8 B[2][4],
                                       const uint16_t* __restrict__ wt,
                                       const char* xsw, const float* yv,
                                       int lmod, int ldiv){
  do_instr_pre<I>(acc, B, xsw, yv, lmod, ldiv);
}

template<int I, int J, int... Rest>
__device__ __forceinline__ void chain1(f32x4* acc, const short8 B[2][4],
                                       const uint16_t* __restrict__ wt,
                                       const char* xsw, const float* yv,
                                       int lmod, int ldiv){
  short8 Bn[2][4];
  load_B<J>(Bn, wt, lmod, ldiv);                 // issue next-B loads NOW
  __builtin_amdgcn_sched_barrier(0);             // pin: no sinking past here
  do_instr_pre<I>(acc, B, xsw, yv, lmod, ldiv);  // compute hides them
  chain1<J, Rest...>(acc, Bn, wt, xsw, yv, lmod, ldiv);
}

// run the instruction chain for a kgroup into acc
template<int D3, int IF, int... Is>
__device__ __forceinline__ void run_chain(f32x4* acc, const uint16_t* __restrict__ wt,
                                          const char* xsw, const float* yv,
                                          int lmod, int ldiv){
  #pragma unroll
  for(int i=0;i<D3*4;++i) acc[i] = (f32x4){0.f,0.f,0.f,0.f};
  short8 B0[2][4];
  load_B<IF>(B0, wt, lmod, ldiv);
  __builtin_amdgcn_sched_barrier(0);
  chain1<IF, Is...>(acc, B0, wt, xsw, yv, lmod, ldiv);
}

// k0: full tile through ost (stride 68), wave-local fences
template<int KOFF, int D3, int IF, int... Is>
__device__ __forceinline__ void kgroup_full(const uint16_t* __restrict__ wt, const char* xsw,
                                            const float* yv, float* __restrict__ outb,
                                            float* __restrict__ ost, int lane,
                                            int lmod, int ldiv)
{
  constexpr int LEN    = 64*D3;
  constexpr int STRIDE = LEN + 4;
  f32x4 acc[D3*4];
  run_chain<D3, IF, Is...>(acc, wt, xsw, yv, lmod, ldiv);

  #pragma unroll
  for(int rt=0; rt<D3; ++rt)
    #pragma unroll
    for(int nt=0;nt<4;++nt)
      #pragma unroll
      for(int j=0;j<4;++j)
        ost[(ldiv*4+j)*STRIDE + (nt*16+lmod)*D3 + rt] = acc[rt*4+nt][j];
  wave_fence();

  const int es2 = lane>>2, oct2 = lane&3;
  #pragma unroll
  for(int c=0;c<LEN/16;++c){
    *(float4*)(outb + (long)es2*576 + KOFF + c*16 + oct2*4) =
      *(const float4*)(ost + es2*STRIDE + c*16 + oct2*4);
  }
  wave_fence();
}

// k1: two nt-pair halves (stride 100)
template<int KOFF, int D3, int IF, int... Is>
__device__ __forceinline__ void kgroup_h(const uint16_t* __restrict__ wt, const char* xsw,
                                         const float* yv, float* __restrict__ outb,
                                         float* __restrict__ ost, int lane,
                                         int lmod, int ldiv)
{
  constexpr int LENH   = 32*D3;
  constexpr int STRIDE = LENH + 4;
  f32x4 acc[D3*4];
  run_chain<D3, IF, Is...>(acc, wt, xsw, yv, lmod, ldiv);

  const int es2 = lane>>2, oct2 = lane&3;
  #pragma unroll
  for(int h=0; h<2; ++h){
    #pragma unroll
    for(int rt=0; rt<D3; ++rt)
      #pragma unroll
      for(int ntl=0; ntl<2; ++ntl)
        #pragma unroll
        for(int j=0;j<4;++j)
          ost[(ldiv*4+j)*STRIDE + (ntl*16+lmod)*D3 + rt] = acc[rt*4 + h*2+ntl][j];
    wave_fence();
    #pragma unroll
    for(int c=0;c<LENH/16;++c){
      *(float4*)(outb + (long)es2*576 + KOFF + h*LENH + c*16 + oct2*4) =
        *(const float4*)(ost + es2*STRIDE + c*16 + oct2*4);
    }
    wave_fence();
  }
}

// k2: four nt-quarters (stride 84)
template<int KOFF, int D3, int IF, int... Is>
__device__ __forceinline__ void kgroup_q(const uint16_t* __restrict__ wt, const char* xsw,
                                         const float* yv, float* __restrict__ outb,
                                         float* __restrict__ ost, int lane,
                                         int lmod, int ldiv)
{
  constexpr int LENQ   = 16*D3;
  constexpr int STRIDE = LENQ + 4;
  f32x4 acc[D3*4];
  run_chain<D3, IF, Is...>(acc, wt, xsw, yv, lmod, ldiv);

  const int es2 = lane>>2, oct2 = lane&3;
  #pragma unroll
  for(int q=0; q<4; ++q){
    #pragma unroll
    for(int rt=0; rt<D3; ++rt)
      #pragma unroll
      for(int j=0;j<4;++j)
        ost[(ldiv*4+j)*STRIDE + lmod*D3 + rt] = acc[rt*4 + q][j];
    wave_fence();
    #pragma unroll
    for(int c=0;c<LENQ/16;++c){
      *(float4*)(outb + (long)es2*576 + KOFF + q*LENQ + c*16 + oct2*4) =
        *(const float4*)(ost + es2*STRIDE + c*16 + oct2*4);
    }
    wave_fence();
  }
}

// ---------------- main kernel: TWO waves per block, 16 shared edges ----------
__global__ __launch_bounds__(128,2) void tp_main(const float* __restrict__ x,
                                                 const float* __restrict__ y,
                                                 const uint16_t* __restrict__ wt,
                                                 float* __restrict__ out)
{
  __shared__ char  xlds[18432] __attribute__((aligned(16)));
  __shared__ float ost0[1600]  __attribute__((aligned(16)));   // wave0: k0/k1
  __shared__ float ost1[1344]  __attribute__((aligned(16)));   // wave1: k2
  const int tid  = threadIdx.x;
  const int wave = tid>>6, lane = tid&63;
  const int lmod = lane&15, ldiv = lane>>4;
  const long nE = (long)blockIdx.x*NE_W;
  char* xsw = xlds;

  // per-lane y: compute edge e = lmod (both waves need it)
  float yv[9];
  {
    const float* yp = y + (nE + lmod)*9;
    #pragma unroll
    for(int q=0;q<9;++q) yv[q] = yp[q];
  }

  // ---- stage x (16 edges) with ALL 128 threads: R7-PROVEN 8-lane/edge pack ----
  {
    const int es = tid>>3, oct = tid&7;          // edge 0..15, u-block 0..7
    const float* xr = x + (nE+es)*576;
    uint32_t xp[9][4];   // xp[pidx][a] = bf16 pair (u=oct*8+2a, u=oct*8+2a+1)

    const float4 a0 = *(const float4*)(xr + oct*8);
    const float4 a1 = *(const float4*)(xr + oct*8 + 4);
    xp[0][0]=pk2c(a0.x,a0.y); xp[0][1]=pk2c(a0.z,a0.w);
    xp[0][2]=pk2c(a1.x,a1.y); xp[0][3]=pk2c(a1.z,a1.w);
    float f1[24];
    {
      const float4* p1 = (const float4*)(xr + 64 + oct*24);
      #pragma unroll
      for(int i=0;i<6;++i){ float4 v=p1[i]; f1[4*i]=v.x; f1[4*i+1]=v.y; f1[4*i+2]=v.z; f1[4*i+3]=v.w; }
    }
    #pragma unroll
    for(int p=0;p<3;++p)
      #pragma unroll
      for(int a=0;a<4;++a) xp[1+p][a] = pk2c(f1[(2*a)*3+p], f1[(2*a+1)*3+p]);
    float f2[40];
    {
      const float4* p2 = (const float4*)(xr + 256 + oct*40);
      #pragma unroll
      for(int i=0;i<10;++i){ float4 v=p2[i]; f2[4*i]=v.x; f2[4*i+1]=v.y; f2[4*i+2]=v.z; f2[4*i+3]=v.w; }
    }
    #pragma unroll
    for(int p=0;p<5;++p)
      #pragma unroll
      for(int a=0;a<4;++a) xp[4+p][a] = pk2c(f2[(2*a)*5+p], f2[(2*a+1)*5+p]);

    // 9 ds_write_b128: row rho = es*9+pidx, chunk oct at position oct^(rho&7)
    #pragma unroll
    for(int pidx=0;pidx<9;++pidx){
      const int rho = es*9 + pidx;
      *(u32x4*)(xsw + rho*128 + ((oct ^ (rho&7))<<4)) = *(const u32x4*)&xp[pidx][0];
    }
  }

  // the ONE real barrier: both waves' staging visible to both waves
  __syncthreads();

  float* outb = out + nE*576;
  if(wave == 0){
    // k0 (l3=0, koff 0):   I = 0:(000) 4:(110) 9:(220)
    kgroup_full<0,  1, 0,4,9   >(wt, xsw, yv, outb, ost0, lane, lmod, ldiv);
    // k1 (l3=1, koff 64):  I = 1:(011) 3:(101) 6:(121) 8:(211)
    kgroup_h   <64, 3, 1,3,6,8 >(wt, xsw, yv, outb, ost0, lane, lmod, ldiv);
  } else {
    // k2 (l3=2, koff 256): I = 2:(022) 5:(112) 7:(202) 10:(222)
    kgroup_q   <256,5, 2,5,7,10>(wt, xsw, yv, outb, ost1, lane, lmod, ldiv);
  }
}

// ---------------- launch ----------------
extern "C" void kernel_launch(void* const* d_in, const int* in_sizes, int n_in,
                              void* d_out, int out_size, void* d_ws, size_t ws_size,
                              hipStream_t stream)
{
  const float* x = (const float*)d_in[0];
  const float* y = (const float*)d_in[1];
  const float* w = (const float*)d_in[2];
  uint16_t* wt = (uint16_t*)d_ws;                 // 11*4096*2 = 90112 B
  prep_w<<<176, 256, 0, stream>>>(w, wt);
  tp_main<<<NBLK, 128, 0, stream>>>(x, y, wt, (float*)d_out);
}

// Round 18
// 128.512 us; speedup vs baseline: 1.7238x; 1.0137x over previous
//
#include <hip/hip_runtime.h>
#include <hip/hip_bf16.h>
#include <stdint.h>

// ---------------------------------------------------------------------------
// OEQTensorProduct: x[N,576] (64x{0e,1o,2e}) (x) y[N,9] ({0e,1o,2e}) -> out[N,576]
// R18 = R17 (130.3us: 2-wave blocks sharing 16-edge x-tile; wave0=k0+k1,
// wave1=k2) with CHEAP FENCES:
//   - intra-kgroup fences are lgkmcnt(0)-only (correctness: ds_write->ds_read
//     ordering and ds_read-before-ost-overwrite; stores capture data in regs;
//     compiler handles store-reg hazards with counted vmcnt). R12 PROVED
//     lgkm-only fences are correct.
//   - ONE vmcnt(0) store-drain per kgroup (3/block, was 14 full drains)
//     keeps the R12-proven store-concurrency bound.
// ---------------------------------------------------------------------------

#define NEDGES 100000
#define NE_W   16                   // edges per block
#define NBLK   (NEDGES/NE_W)        // 6250 two-wave blocks

typedef short    short8 __attribute__((ext_vector_type(8)));
typedef float    f32x4  __attribute__((ext_vector_type(4)));
typedef uint32_t u32x4  __attribute__((ext_vector_type(4)));

// ---------------- compile-time Wigner-3j (real basis) tables ----------------
constexpr int L1A[11] = {0,0,0,1,1,1,1,2,2,2,2};
constexpr int L2A[11] = {0,1,2,0,1,1,2,0,1,2,2};
constexpr int L3A[11] = {0,1,2,1,0,2,1,2,1,0,2};

constexpr double cfact(int n){ double r=1.0; for(int i=2;i<=n;++i) r*=(double)i; return r; }
constexpr double csqrt(double x){ if(x<=0.0) return 0.0; double g = x>1.0?x:1.0;
                                 for(int i=0;i<80;++i) g=0.5*(g+x/g); return g; }
constexpr int imax2(int a,int b){return a>b?a:b;}
constexpr int imin2(int a,int b){return a<b?a:b;}

constexpr double su2_cg(int j1,int j2,int j3,int m1,int m2,int m3){
  if(m3 != m1+m2) return 0.0;
  int vmin = imax2(imax2(-j1+j2+m3, -j1+m1), 0);
  int vmax = imin2(imin2(j2+j3+m1, j3-j1+j2), j3+m3);
  double c = csqrt((double)(2*j3+1)*cfact(j3+j1-j2)*cfact(j3-j1+j2)*cfact(j1+j2-j3)
                   *cfact(j3+m3)*cfact(j3-m3)
                   /(cfact(j1+j2+j3+1)*cfact(j1-m1)*cfact(j1+m1)*cfact(j2-m2)*cfact(j2+m2)));
  double s=0.0;
  for(int v=vmin; v<=vmax; ++v){
    double sg = ((v+j2+m2)&1)? -1.0 : 1.0;
    s += sg*cfact(j2+j3+m1-v)*cfact(j1-m1+v)
         /(cfact(v)*cfact(j3-j1+j2-v)*cfact(j3+m3-v)*cfact(j1-j2-m3+v));
  }
  return c*s;
}

struct Cplx{ double re, im; };
struct Q55 { Cplx q[5][5]; };

constexpr Q55 change_basis(int l){
  Q55 Q{};
  const double is2 = 1.0/csqrt(2.0);
  for(int m=-l;m<0;++m){
    Q.q[l+m][l-m].re =  is2;
    Q.q[l+m][l+m].im = -is2;
  }
  Q.q[l][l].re = 1.0;
  for(int m=1;m<=l;++m){
    double s = (m&1)? -1.0 : 1.0;
    Q.q[l+m][l+m].re = s*is2;
    Q.q[l+m][l-m].im = s*is2;
  }
  for(int i=0;i<5;++i) for(int j=0;j<5;++j){
    double re=Q.q[i][j].re, im=Q.q[i][j].im;
    if(l==1){ Q.q[i][j].re = im;  Q.q[i][j].im = -re; }
    else if(l==2){ Q.q[i][j].re = -re; Q.q[i][j].im = -im; }
  }
  return Q;
}

struct Tbl {
  double C[11][5][5][5];   // [I][p][q][r]
  double alpha[11];
};

constexpr Tbl build_tbl(){
  Tbl T{};
  for(int I=0;I<11;++I){
    const int l1=L1A[I], l2=L2A[I], l3=L3A[I];
    const int D1=2*l1+1, D2=2*l2+1, D3=2*l3+1;
    double cg[5][5][5]{};
    for(int a=0;a<D1;++a)for(int b=0;b<D2;++b){
      int m3 = (a-l1)+(b-l2);
      if(m3>=-l3 && m3<=l3) cg[a][b][l3+m3] = su2_cg(l1,l2,l3,a-l1,b-l2,m3);
    }
    Q55 q1 = change_basis(l1), q2 = change_basis(l2), q3 = change_basis(l3);
    Cplx T1[5][5][5]{};
    for(int i=0;i<D1;++i)for(int b=0;b<D2;++b)for(int c=0;c<D3;++c){
      double re=0,im=0;
      for(int a=0;a<D1;++a){ re += q1.q[a][i].re*cg[a][b][c]; im += q1.q[a][i].im*cg[a][b][c]; }
      T1[i][b][c].re=re; T1[i][b][c].im=im;
    }
    Cplx T2[5][5][5]{};
    for(int i=0;i<D1;++i)for(int j=0;j<D2;++j)for(int c=0;c<D3;++c){
      double re=0,im=0;
      for(int b=0;b<D2;++b){
        double qr=q2.q[b][j].re, qi=q2.q[b][j].im;
        re += qr*T1[i][b][c].re - qi*T1[i][b][c].im;
        im += qr*T1[i][b][c].im + qi*T1[i][b][c].re;
      }
      T2[i][j][c].re=re; T2[i][j][c].im=im;
    }
    double nrm2 = 0.0;
    for(int i=0;i<D1;++i)for(int j=0;j<D2;++j)for(int k=0;k<D3;++k){
      double re=0;
      for(int c=0;c<D3;++c){
        double qr=q3.q[c][k].re, qi=-q3.q[c][k].im;   // conj
        re += qr*T2[i][j][c].re - qi*T2[i][j][c].im;
      }
      T.C[I][i][j][k] = re; nrm2 += re*re;
    }
    double nrm = csqrt(nrm2);
    if(nrm > 0.0)
      for(int i=0;i<D1;++i)for(int j=0;j<D2;++j)for(int k=0;k<D3;++k) T.C[I][i][j][k] /= nrm;
    const int fan = (l3==0)?192:256;
    T.alpha[I] = csqrt((double)(2*l3+1)/(double)fan);
  }
  return T;
}

constexpr Tbl TBL = build_tbl();

__device__ const float c_alpha[11] = {
  (float)TBL.alpha[0],(float)TBL.alpha[1],(float)TBL.alpha[2],(float)TBL.alpha[3],
  (float)TBL.alpha[4],(float)TBL.alpha[5],(float)TBL.alpha[6],(float)TBL.alpha[7],
  (float)TBL.alpha[8],(float)TBL.alpha[9],(float)TBL.alpha[10]
};

// ---------------- device helpers ----------------
__device__ __forceinline__ uint16_t f2bf(float f){      // fp32 -> bf16 RNE
  uint32_t u = __float_as_uint(f);
  return (uint16_t)((u + 0x7fffu + ((u>>16)&1u)) >> 16);
}
// compiler-recognized packed bf16 convert (emits v_cvt_pk_bf16_f32, RNE)
__device__ __forceinline__ uint32_t pk2c(float a, float b){
  __hip_bfloat162 h = __float22bfloat162_rn(float2{a,b});
  uint32_t r; __builtin_memcpy(&r, &h, 4); return r;
}
// cheap LDS-only fence (R12-proven correct): orders this wave's ds ops
__device__ __forceinline__ void lds_fence(){
  asm volatile("s_waitcnt lgkmcnt(0)" ::: "memory");
  __builtin_amdgcn_sched_barrier(0);
}
// store drain: bounds in-flight global stores (R12 lesson), 1x per kgroup
__device__ __forceinline__ void store_drain(){
  asm volatile("s_waitcnt vmcnt(0)" ::: "memory");
  __builtin_amdgcn_sched_barrier(0);
}

// ---------------- W pre-transform: Wt[I][w][u] = bf16(alpha_I * W[I][u][w]) ----
__global__ __launch_bounds__(256) void prep_w(const float* __restrict__ w,
                                              uint16_t* __restrict__ wt){
  int tid = blockIdx.x*256 + threadIdx.x;
  if(tid >= 11*4096) return;
  int I = tid >> 12;
  int rem = tid & 4095;
  int wo = rem >> 6, u = rem & 63;
  wt[tid] = f2bf(c_alpha[I] * w[(I<<12) + (u<<6) + wo]);
}

// ---------------------------------------------------------------------------
// xlds (18432 B): row rho = e*9 + pidx (e<16), 64 u's x 2B = 128 B;
// 16-B chunk s (u = s*8..s*8+7) stored at position s ^ (rho&7).
// ost0 (1600 fl, wave0): k0 stride 68 / k1 h-split stride 100.
// ost1 (1344 fl, wave1): k2 q-split stride 84. All strides == 4 mod 32.
// ---------------------------------------------------------------------------

// B-fragment load: 8x global_load_dwordx4 from wt
template<int I>
__device__ __forceinline__ void load_B(short8 B[2][4], const uint16_t* __restrict__ wt,
                                       int lmod, int ldiv){
  #pragma unroll
  for(int ks=0;ks<2;++ks)
    #pragma unroll
    for(int nt=0;nt<4;++nt)
      B[ks][nt] = *(const short8*)(wt + (I*64 + nt*16 + lmod)*64 + ks*32 + ldiv*8);
}

// one instruction with preloaded B (16-edge mapping, R16-proven):
// A-frag: lane computes z[u=ks*32+ldiv*8+i][e=lmod, r=rt]; acc[rt*4+nt]
template<int I>
__device__ __forceinline__ void do_instr_pre(f32x4* acc, const short8 B[2][4],
                                             const char* xsw, const float* yv,
                                             int lmod, int ldiv)
{
  constexpr int l1=L1A[I], l2=L2A[I], l3=L3A[I];
  constexpr int D1=2*l1+1, D2=2*l2+1, D3=2*l3+1;
  constexpr int PB=(l1==0)?0:((l1==1)?1:4);
  constexpr int QB=(l2==0)?0:((l2==1)?1:4);

  float M[D1][D3];
  #pragma unroll
  for(int p=0;p<D1;++p)
    #pragma unroll
    for(int r=0;r<D3;++r){
      float m=0.f;
      #pragma unroll
      for(int q=0;q<D2;++q){
        const float cc = (float)TBL.C[I][p][q][r];
        if(cc != 0.0f) m = fmaf(cc, yv[QB+q], m);
      }
      M[p][r]=m;
    }

  #pragma unroll
  for(int ks=0;ks<2;++ks){
    float xf[D1][8];
    #pragma unroll
    for(int p=0;p<D1;++p){
      const int rho  = lmod*9 + PB + p;
      const int addr = rho*128 + (((ks*4+ldiv) ^ (rho&7))<<4);
      const u32x4 xv = *(const u32x4*)(xsw + addr);
      #pragma unroll
      for(int k=0;k<4;++k){
        xf[p][2*k]   = __uint_as_float(xv[k]<<16);
        xf[p][2*k+1] = __uint_as_float(xv[k]&0xffff0000u);
      }
    }
    #pragma unroll
    for(int rt=0;rt<D3;++rt){
      float zf[8];
      #pragma unroll
      for(int i=0;i<8;++i) zf[i]=0.f;
      #pragma unroll
      for(int p=0;p<D1;++p)
        #pragma unroll
        for(int i=0;i<8;++i) zf[i] = fmaf(M[p][rt], xf[p][i], zf[i]);
      u32x4 av = { pk2c(zf[0],zf[1]), pk2c(zf[2],zf[3]),
                   pk2c(zf[4],zf[5]), pk2c(zf[6],zf[7]) };
      const short8 A = *(const short8*)&av;
      #pragma unroll
      for(int nt=0;nt<4;++nt)
        acc[rt*4+nt] = __builtin_amdgcn_mfma_f32_16x16x32_bf16(A, B[ks][nt], acc[rt*4+nt], 0,0,0);
    }
  }
}

// pinned prefetch chain (R13-proven)
template<int I>
__device__ __forceinline__ void chain1(f32x4* acc, const short8 B[2][4],
                                       const uint16_t* __restrict__ wt,
                                       const char* xsw, const float* yv,
                                       int lmod, int ldiv){
  do_instr_pre<I>(acc, B, xsw, yv, lmod, ldiv);
}

template<int I, int J, int... Rest>
__device__ __forceinline__ void chain1(f32x4* acc, const short8 B[2][4],
                                       const uint16_t* __restrict__ wt,
                                       const char* xsw, const float* yv,
                                       int lmod, int ldiv){
  short8 Bn[2][4];
  load_B<J>(Bn, wt, lmod, ldiv);                 // issue next-B loads NOW
  __builtin_amdgcn_sched_barrier(0);             // pin: no sinking past here
  do_instr_pre<I>(acc, B, xsw, yv, lmod, ldiv);  // compute hides them
  chain1<J, Rest...>(acc, Bn, wt, xsw, yv, lmod, ldiv);
}

// run the instruction chain for a kgroup into acc
template<int D3, int IF, int... Is>
__device__ __forceinline__ void run_chain(f32x4* acc, const uint16_t* __restrict__ wt,
                                          const char* xsw, const float* yv,
                                          int lmod, int ldiv){
  #pragma unroll
  for(int i=0;i<D3*4;++i) acc[i] = (f32x4){0.f,0.f,0.f,0.f};
  short8 B0[2][4];
  load_B<IF>(B0, wt, lmod, ldiv);
  __builtin_amdgcn_sched_barrier(0);
  chain1<IF, Is...>(acc, B0, wt, xsw, yv, lmod, ldiv);
}

// k0: full tile through ost (stride 68)
template<int KOFF, int D3, int IF, int... Is>
__device__ __forceinline__ void kgroup_full(const uint16_t* __restrict__ wt, const char* xsw,
                                            const float* yv, float* __restrict__ outb,
                                            float* __restrict__ ost, int lane,
                                            int lmod, int ldiv)
{
  constexpr int LEN    = 64*D3;
  constexpr int STRIDE = LEN + 4;
  f32x4 acc[D3*4];
  run_chain<D3, IF, Is...>(acc, wt, xsw, yv, lmod, ldiv);

  #pragma unroll
  for(int rt=0; rt<D3; ++rt)
    #pragma unroll
    for(int nt=0;nt<4;++nt)
      #pragma unroll
      for(int j=0;j<4;++j)
        ost[(ldiv*4+j)*STRIDE + (nt*16+lmod)*D3 + rt] = acc[rt*4+nt][j];
  lds_fence();                      // ds_writes visible to own ds_reads

  const int es2 = lane>>2, oct2 = lane&3;
  #pragma unroll
  for(int c=0;c<LEN/16;++c){
    *(float4*)(outb + (long)es2*576 + KOFF + c*16 + oct2*4) =
      *(const float4*)(ost + es2*STRIDE + c*16 + oct2*4);
  }
  lds_fence();                      // ds_reads done before ost reuse
  store_drain();                    // per-kgroup store-concurrency bound
}

// k1: two nt-pair halves (stride 100)
template<int KOFF, int D3, int IF, int... Is>
__device__ __forceinline__ void kgroup_h(const uint16_t* __restrict__ wt, const char* xsw,
                                         const float* yv, float* __restrict__ outb,
                                         float* __restrict__ ost, int lane,
                                         int lmod, int ldiv)
{
  constexpr int LENH   = 32*D3;
  constexpr int STRIDE = LENH + 4;
  f32x4 acc[D3*4];
  run_chain<D3, IF, Is...>(acc, wt, xsw, yv, lmod, ldiv);

  const int es2 = lane>>2, oct2 = lane&3;
  #pragma unroll
  for(int h=0; h<2; ++h){
    #pragma unroll
    for(int rt=0; rt<D3; ++rt)
      #pragma unroll
      for(int ntl=0; ntl<2; ++ntl)
        #pragma unroll
        for(int j=0;j<4;++j)
          ost[(ldiv*4+j)*STRIDE + (ntl*16+lmod)*D3 + rt] = acc[rt*4 + h*2+ntl][j];
    lds_fence();
    #pragma unroll
    for(int c=0;c<LENH/16;++c){
      *(float4*)(outb + (long)es2*576 + KOFF + h*LENH + c*16 + oct2*4) =
        *(const float4*)(ost + es2*STRIDE + c*16 + oct2*4);
    }
    lds_fence();
  }
  store_drain();                    // once per kgroup
}

// k2: four nt-quarters (stride 84)
template<int KOFF, int D3, int IF, int... Is>
__device__ __forceinline__ void kgroup_q(const uint16_t* __restrict__ wt, const char* xsw,
                                         const float* yv, float* __restrict__ outb,
                                         float* __restrict__ ost, int lane,
                                         int lmod, int ldiv)
{
  constexpr int LENQ   = 16*D3;
  constexpr int STRIDE = LENQ + 4;
  f32x4 acc[D3*4];
  run_chain<D3, IF, Is...>(acc, wt, xsw, yv, lmod, ldiv);

  const int es2 = lane>>2, oct2 = lane&3;
  #pragma unroll
  for(int q=0; q<4; ++q){
    #pragma unroll
    for(int rt=0; rt<D3; ++rt)
      #pragma unroll
      for(int j=0;j<4;++j)
        ost[(ldiv*4+j)*STRIDE + lmod*D3 + rt] = acc[rt*4 + q][j];
    lds_fence();
    #pragma unroll
    for(int c=0;c<LENQ/16;++c){
      *(float4*)(outb + (long)es2*576 + KOFF + q*LENQ + c*16 + oct2*4) =
        *(const float4*)(ost + es2*STRIDE + c*16 + oct2*4);
    }
    lds_fence();
  }
  store_drain();                    // once per kgroup
}

// ---------------- main kernel: TWO waves per block, 16 shared edges ----------
__global__ __launch_bounds__(128,2) void tp_main(const float* __restrict__ x,
                                                 const float* __restrict__ y,
                                                 const uint16_t* __restrict__ wt,
                                                 float* __restrict__ out)
{
  __shared__ char  xlds[18432] __attribute__((aligned(16)));
  __shared__ float ost0[1600]  __attribute__((aligned(16)));   // wave0: k0/k1
  __shared__ float ost1[1344]  __attribute__((aligned(16)));   // wave1: k2
  const int tid  = threadIdx.x;
  const int wave = tid>>6, lane = tid&63;
  const int lmod = lane&15, ldiv = lane>>4;
  const long nE = (long)blockIdx.x*NE_W;
  char* xsw = xlds;

  // per-lane y: compute edge e = lmod (both waves need it)
  float yv[9];
  {
    const float* yp = y + (nE + lmod)*9;
    #pragma unroll
    for(int q=0;q<9;++q) yv[q] = yp[q];
  }

  // ---- stage x (16 edges) with ALL 128 threads: R7-PROVEN 8-lane/edge pack ----
  {
    const int es = tid>>3, oct = tid&7;          // edge 0..15, u-block 0..7
    const float* xr = x + (nE+es)*576;
    uint32_t xp[9][4];   // xp[pidx][a] = bf16 pair (u=oct*8+2a, u=oct*8+2a+1)

    const float4 a0 = *(const float4*)(xr + oct*8);
    const float4 a1 = *(const float4*)(xr + oct*8 + 4);
    xp[0][0]=pk2c(a0.x,a0.y); xp[0][1]=pk2c(a0.z,a0.w);
    xp[0][2]=pk2c(a1.x,a1.y); xp[0][3]=pk2c(a1.z,a1.w);
    float f1[24];
    {
      const float4* p1 = (const float4*)(xr + 64 + oct*24);
      #pragma unroll
      for(int i=0;i<6;++i){ float4 v=p1[i]; f1[4*i]=v.x; f1[4*i+1]=v.y; f1[4*i+2]=v.z; f1[4*i+3]=v.w; }
    }
    #pragma unroll
    for(int p=0;p<3;++p)
      #pragma unroll
      for(int a=0;a<4;++a) xp[1+p][a] = pk2c(f1[(2*a)*3+p], f1[(2*a+1)*3+p]);
    float f2[40];
    {
      const float4* p2 = (const float4*)(xr + 256 + oct*40);
      #pragma unroll
      for(int i=0;i<10;++i){ float4 v=p2[i]; f2[4*i]=v.x; f2[4*i+1]=v.y; f2[4*i+2]=v.z; f2[4*i+3]=v.w; }
    }
    #pragma unroll
    for(int p=0;p<5;++p)
      #pragma unroll
      for(int a=0;a<4;++a) xp[4+p][a] = pk2c(f2[(2*a)*5+p], f2[(2*a+1)*5+p]);

    // 9 ds_write_b128: row rho = es*9+pidx, chunk oct at position oct^(rho&7)
    #pragma unroll
    for(int pidx=0;pidx<9;++pidx){
      const int rho = es*9 + pidx;
      *(u32x4*)(xsw + rho*128 + ((oct ^ (rho&7))<<4)) = *(const u32x4*)&xp[pidx][0];
    }
  }

  // the ONE real barrier: both waves' staging visible to both waves
  __syncthreads();

  float* outb = out + nE*576;
  if(wave == 0){
    // k0 (l3=0, koff 0):   I = 0:(000) 4:(110) 9:(220)
    kgroup_full<0,  1, 0,4,9   >(wt, xsw, yv, outb, ost0, lane, lmod, ldiv);
    // k1 (l3=1, koff 64):  I = 1:(011) 3:(101) 6:(121) 8:(211)
    kgroup_h   <64, 3, 1,3,6,8 >(wt, xsw, yv, outb, ost0, lane, lmod, ldiv);
  } else {
    // k2 (l3=2, koff 256): I = 2:(022) 5:(112) 7:(202) 10:(222)
    kgroup_q   <256,5, 2,5,7,10>(wt, xsw, yv, outb, ost1, lane, lmod, ldiv);
  }
}

// ---------------- launch ----------------
extern "C" void kernel_launch(void* const* d_in, const int* in_sizes, int n_in,
                              void* d_out, int out_size, void* d_ws, size_t ws_size,
                              hipStream_t stream)
{
  const float* x = (const float*)d_in[0];
  const float* y = (const float*)d_in[1];
  const float* w = (const float*)d_in[2];
  uint16_t* wt = (uint16_t*)d_ws;                 // 11*4096*2 = 90112 B
  prep_w<<<176, 256, 0, stream>>>(w, wt);
  tp_main<<<NBLK, 128, 0, stream>>>(x, y, wt, (float*)d_out);
}

// Round 19
// 128.143 us; speedup vs baseline: 1.7287x; 1.0029x over previous
//
#include <hip/hip_runtime.h>
#include <hip/hip_bf16.h>
#include <stdint.h>

// ---------------------------------------------------------------------------
// OEQTensorProduct: x[N,576] (64x{0e,1o,2e}) (x) y[N,9] ({0e,1o,2e}) -> out[N,576]
// R19 = R18 (128.5us: 2-wave blocks sharing 16-edge x-tile; wave0=k0+k1,
// wave1=k2; lgkm-only fences + 1 store-drain per kgroup) with FINER OST
// SPLITS to raise the LDS block cap:
//   k0: h-split (stride 36, 2304 B)   [was full, stride 68]
//   k1: q-split (stride 52, 3328 B)   [was h-split, stride 100]
//   k2: q-split (stride 84, 5376 B)   [unchanged]
// LDS 30208 -> 27136 B => 6 blocks/CU x 2 waves = 12-wave cap (was 10).
// Extra fences are the lgkm-only kind R18 proved cheap. All out-chunks stay
// >=64B-aligned contiguous per edge (no partial-line RMW).
// ---------------------------------------------------------------------------

#define NEDGES 100000
#define NE_W   16                   // edges per block
#define NBLK   (NEDGES/NE_W)        // 6250 two-wave blocks

typedef short    short8 __attribute__((ext_vector_type(8)));
typedef float    f32x4  __attribute__((ext_vector_type(4)));
typedef uint32_t u32x4  __attribute__((ext_vector_type(4)));

// ---------------- compile-time Wigner-3j (real basis) tables ----------------
constexpr int L1A[11] = {0,0,0,1,1,1,1,2,2,2,2};
constexpr int L2A[11] = {0,1,2,0,1,1,2,0,1,2,2};
constexpr int L3A[11] = {0,1,2,1,0,2,1,2,1,0,2};

constexpr double cfact(int n){ double r=1.0; for(int i=2;i<=n;++i) r*=(double)i; return r; }
constexpr double csqrt(double x){ if(x<=0.0) return 0.0; double g = x>1.0?x:1.0;
                                 for(int i=0;i<80;++i) g=0.5*(g+x/g); return g; }
constexpr int imax2(int a,int b){return a>b?a:b;}
constexpr int imin2(int a,int b){return a<b?a:b;}

constexpr double su2_cg(int j1,int j2,int j3,int m1,int m2,int m3){
  if(m3 != m1+m2) return 0.0;
  int vmin = imax2(imax2(-j1+j2+m3, -j1+m1), 0);
  int vmax = imin2(imin2(j2+j3+m1, j3-j1+j2), j3+m3);
  double c = csqrt((double)(2*j3+1)*cfact(j3+j1-j2)*cfact(j3-j1+j2)*cfact(j1+j2-j3)
                   *cfact(j3+m3)*cfact(j3-m3)
                   /(cfact(j1+j2+j3+1)*cfact(j1-m1)*cfact(j1+m1)*cfact(j2-m2)*cfact(j2+m2)));
  double s=0.0;
  for(int v=vmin; v<=vmax; ++v){
    double sg = ((v+j2+m2)&1)? -1.0 : 1.0;
    s += sg*cfact(j2+j3+m1-v)*cfact(j1-m1+v)
         /(cfact(v)*cfact(j3-j1+j2-v)*cfact(j3+m3-v)*cfact(j1-j2-m3+v));
  }
  return c*s;
}

struct Cplx{ double re, im; };
struct Q55 { Cplx q[5][5]; };

constexpr Q55 change_basis(int l){
  Q55 Q{};
  const double is2 = 1.0/csqrt(2.0);
  for(int m=-l;m<0;++m){
    Q.q[l+m][l-m].re =  is2;
    Q.q[l+m][l+m].im = -is2;
  }
  Q.q[l][l].re = 1.0;
  for(int m=1;m<=l;++m){
    double s = (m&1)? -1.0 : 1.0;
    Q.q[l+m][l+m].re = s*is2;
    Q.q[l+m][l-m].im = s*is2;
  }
  for(int i=0;i<5;++i) for(int j=0;j<5;++j){
    double re=Q.q[i][j].re, im=Q.q[i][j].im;
    if(l==1){ Q.q[i][j].re = im;  Q.q[i][j].im = -re; }
    else if(l==2){ Q.q[i][j].re = -re; Q.q[i][j].im = -im; }
  }
  return Q;
}

struct Tbl {
  double C[11][5][5][5];   // [I][p][q][r]
  double alpha[11];
};

constexpr Tbl build_tbl(){
  Tbl T{};
  for(int I=0;I<11;++I){
    const int l1=L1A[I], l2=L2A[I], l3=L3A[I];
    const int D1=2*l1+1, D2=2*l2+1, D3=2*l3+1;
    double cg[5][5][5]{};
    for(int a=0;a<D1;++a)for(int b=0;b<D2;++b){
      int m3 = (a-l1)+(b-l2);
      if(m3>=-l3 && m3<=l3) cg[a][b][l3+m3] = su2_cg(l1,l2,l3,a-l1,b-l2,m3);
    }
    Q55 q1 = change_basis(l1), q2 = change_basis(l2), q3 = change_basis(l3);
    Cplx T1[5][5][5]{};
    for(int i=0;i<D1;++i)for(int b=0;b<D2;++b)for(int c=0;c<D3;++c){
      double re=0,im=0;
      for(int a=0;a<D1;++a){ re += q1.q[a][i].re*cg[a][b][c]; im += q1.q[a][i].im*cg[a][b][c]; }
      T1[i][b][c].re=re; T1[i][b][c].im=im;
    }
    Cplx T2[5][5][5]{};
    for(int i=0;i<D1;++i)for(int j=0;j<D2;++j)for(int c=0;c<D3;++c){
      double re=0,im=0;
      for(int b=0;b<D2;++b){
        double qr=q2.q[b][j].re, qi=q2.q[b][j].im;
        re += qr*T1[i][b][c].re - qi*T1[i][b][c].im;
        im += qr*T1[i][b][c].im + qi*T1[i][b][c].re;
      }
      T2[i][j][c].re=re; T2[i][j][c].im=im;
    }
    double nrm2 = 0.0;
    for(int i=0;i<D1;++i)for(int j=0;j<D2;++j)for(int k=0;k<D3;++k){
      double re=0;
      for(int c=0;c<D3;++c){
        double qr=q3.q[c][k].re, qi=-q3.q[c][k].im;   // conj
        re += qr*T2[i][j][c].re - qi*T2[i][j][c].im;
      }
      T.C[I][i][j][k] = re; nrm2 += re*re;
    }
    double nrm = csqrt(nrm2);
    if(nrm > 0.0)
      for(int i=0;i<D1;++i)for(int j=0;j<D2;++j)for(int k=0;k<D3;++k) T.C[I][i][j][k] /= nrm;
    const int fan = (l3==0)?192:256;
    T.alpha[I] = csqrt((double)(2*l3+1)/(double)fan);
  }
  return T;
}

constexpr Tbl TBL = build_tbl();

__device__ const float c_alpha[11] = {
  (float)TBL.alpha[0],(float)TBL.alpha[1],(float)TBL.alpha[2],(float)TBL.alpha[3],
  (float)TBL.alpha[4],(float)TBL.alpha[5],(float)TBL.alpha[6],(float)TBL.alpha[7],
  (float)TBL.alpha[8],(float)TBL.alpha[9],(float)TBL.alpha[10]
};

// ---------------- device helpers ----------------
__device__ __forceinline__ uint16_t f2bf(float f){      // fp32 -> bf16 RNE
  uint32_t u = __float_as_uint(f);
  return (uint16_t)((u + 0x7fffu + ((u>>16)&1u)) >> 16);
}
// compiler-recognized packed bf16 convert (emits v_cvt_pk_bf16_f32, RNE)
__device__ __forceinline__ uint32_t pk2c(float a, float b){
  __hip_bfloat162 h = __float22bfloat162_rn(float2{a,b});
  uint32_t r; __builtin_memcpy(&r, &h, 4); return r;
}
// cheap LDS-only fence (R12/R18-proven correct): orders this wave's ds ops
__device__ __forceinline__ void lds_fence(){
  asm volatile("s_waitcnt lgkmcnt(0)" ::: "memory");
  __builtin_amdgcn_sched_barrier(0);
}
// store drain: bounds in-flight global stores (R12 lesson), 1x per kgroup
__device__ __forceinline__ void store_drain(){
  asm volatile("s_waitcnt vmcnt(0)" ::: "memory");
  __builtin_amdgcn_sched_barrier(0);
}

// ---------------- W pre-transform: Wt[I][w][u] = bf16(alpha_I * W[I][u][w]) ----
__global__ __launch_bounds__(256) void prep_w(const float* __restrict__ w,
                                              uint16_t* __restrict__ wt){
  int tid = blockIdx.x*256 + threadIdx.x;
  if(tid >= 11*4096) return;
  int I = tid >> 12;
  int rem = tid & 4095;
  int wo = rem >> 6, u = rem & 63;
  wt[tid] = f2bf(c_alpha[I] * w[(I<<12) + (u<<6) + wo]);
}

// ---------------------------------------------------------------------------
// xlds (18432 B): row rho = e*9 + pidx (e<16), 64 u's x 2B = 128 B;
// 16-B chunk s (u = s*8..s*8+7) stored at position s ^ (rho&7).
// ost0 (832 fl = 3328 B, wave0): k0 h-split stride 36 / k1 q-split stride 52.
// ost1 (1344 fl = 5376 B, wave1): k2 q-split stride 84. All == 4 mod 32.
// Total LDS 27136 B => 6 blocks/CU.
// ---------------------------------------------------------------------------

// B-fragment load: 8x global_load_dwordx4 from wt
template<int I>
__device__ __forceinline__ void load_B(short8 B[2][4], const uint16_t* __restrict__ wt,
                                       int lmod, int ldiv){
  #pragma unroll
  for(int ks=0;ks<2;++ks)
    #pragma unroll
    for(int nt=0;nt<4;++nt)
      B[ks][nt] = *(const short8*)(wt + (I*64 + nt*16 + lmod)*64 + ks*32 + ldiv*8);
}

// one instruction with preloaded B (16-edge mapping, R16-proven):
// A-frag: lane computes z[u=ks*32+ldiv*8+i][e=lmod, r=rt]; acc[rt*4+nt]
template<int I>
__device__ __forceinline__ void do_instr_pre(f32x4* acc, const short8 B[2][4],
                                             const char* xsw, const float* yv,
                                             int lmod, int ldiv)
{
  constexpr int l1=L1A[I], l2=L2A[I], l3=L3A[I];
  constexpr int D1=2*l1+1, D2=2*l2+1, D3=2*l3+1;
  constexpr int PB=(l1==0)?0:((l1==1)?1:4);
  constexpr int QB=(l2==0)?0:((l2==1)?1:4);

  float M[D1][D3];
  #pragma unroll
  for(int p=0;p<D1;++p)
    #pragma unroll
    for(int r=0;r<D3;++r){
      float m=0.f;
      #pragma unroll
      for(int q=0;q<D2;++q){
        const float cc = (float)TBL.C[I][p][q][r];
        if(cc != 0.0f) m = fmaf(cc, yv[QB+q], m);
      }
      M[p][r]=m;
    }

  #pragma unroll
  for(int ks=0;ks<2;++ks){
    float xf[D1][8];
    #pragma unroll
    for(int p=0;p<D1;++p){
      const int rho  = lmod*9 + PB + p;
      const int addr = rho*128 + (((ks*4+ldiv) ^ (rho&7))<<4);
      const u32x4 xv = *(const u32x4*)(xsw + addr);
      #pragma unroll
      for(int k=0;k<4;++k){
        xf[p][2*k]   = __uint_as_float(xv[k]<<16);
        xf[p][2*k+1] = __uint_as_float(xv[k]&0xffff0000u);
      }
    }
    #pragma unroll
    for(int rt=0;rt<D3;++rt){
      float zf[8];
      #pragma unroll
      for(int i=0;i<8;++i) zf[i]=0.f;
      #pragma unroll
      for(int p=0;p<D1;++p)
        #pragma unroll
        for(int i=0;i<8;++i) zf[i] = fmaf(M[p][rt], xf[p][i], zf[i]);
      u32x4 av = { pk2c(zf[0],zf[1]), pk2c(zf[2],zf[3]),
                   pk2c(zf[4],zf[5]), pk2c(zf[6],zf[7]) };
      const short8 A = *(const short8*)&av;
      #pragma unroll
      for(int nt=0;nt<4;++nt)
        acc[rt*4+nt] = __builtin_amdgcn_mfma_f32_16x16x32_bf16(A, B[ks][nt], acc[rt*4+nt], 0,0,0);
    }
  }
}

// pinned prefetch chain (R13-proven)
template<int I>
__device__ __forceinline__ void chain1(f32x4* acc, const short8 B[2][4],
                                       const uint16_t* __restrict__ wt,
                                       const char* xsw, const float* yv,
                                       int lmod, int ldiv){
  do_instr_pre<I>(acc, B, xsw, yv, lmod, ldiv);
}

template<int I, int J, int... Rest>
__device__ __forceinline__ void chain1(f32x4* acc, const short8 B[2][4],
                                       const uint16_t* __restrict__ wt,
                                       const char* xsw, const float* yv,
                                       int lmod, int ldiv){
  short8 Bn[2][4];
  load_B<J>(Bn, wt, lmod, ldiv);                 // issue next-B loads NOW
  __builtin_amdgcn_sched_barrier(0);             // pin: no sinking past here
  do_instr_pre<I>(acc, B, xsw, yv, lmod, ldiv);  // compute hides them
  chain1<J, Rest...>(acc, Bn, wt, xsw, yv, lmod, ldiv);
}

// run the instruction chain for a kgroup into acc
template<int D3, int IF, int... Is>
__device__ __forceinline__ void run_chain(f32x4* acc, const uint16_t* __restrict__ wt,
                                          const char* xsw, const float* yv,
                                          int lmod, int ldiv){
  #pragma unroll
  for(int i=0;i<D3*4;++i) acc[i] = (f32x4){0.f,0.f,0.f,0.f};
  short8 B0[2][4];
  load_B<IF>(B0, wt, lmod, ldiv);
  __builtin_amdgcn_sched_barrier(0);
  chain1<IF, Is...>(acc, B0, wt, xsw, yv, lmod, ldiv);
}

// h-split kgroup: two nt-pair halves (stride 32*D3+4)
template<int KOFF, int D3, int IF, int... Is>
__device__ __forceinline__ void kgroup_h(const uint16_t* __restrict__ wt, const char* xsw,
                                         const float* yv, float* __restrict__ outb,
                                         float* __restrict__ ost, int lane,
                                         int lmod, int ldiv)
{
  constexpr int LENH   = 32*D3;
  constexpr int STRIDE = LENH + 4;
  f32x4 acc[D3*4];
  run_chain<D3, IF, Is...>(acc, wt, xsw, yv, lmod, ldiv);

  const int es2 = lane>>2, oct2 = lane&3;
  #pragma unroll
  for(int h=0; h<2; ++h){
    #pragma unroll
    for(int rt=0; rt<D3; ++rt)
      #pragma unroll
      for(int ntl=0; ntl<2; ++ntl)
        #pragma unroll
        for(int j=0;j<4;++j)
          ost[(ldiv*4+j)*STRIDE + (ntl*16+lmod)*D3 + rt] = acc[rt*4 + h*2+ntl][j];
    lds_fence();
    #pragma unroll
    for(int c=0;c<LENH/16;++c){
      *(float4*)(outb + (long)es2*576 + KOFF + h*LENH + c*16 + oct2*4) =
        *(const float4*)(ost + es2*STRIDE + c*16 + oct2*4);
    }
    lds_fence();
  }
  store_drain();                    // once per kgroup
}

// q-split kgroup: four nt-quarters (stride 16*D3+4)
template<int KOFF, int D3, int IF, int... Is>
__device__ __forceinline__ void kgroup_q(const uint16_t* __restrict__ wt, const char* xsw,
                                         const float* yv, float* __restrict__ outb,
                                         float* __restrict__ ost, int lane,
                                         int lmod, int ldiv)
{
  constexpr int LENQ   = 16*D3;
  constexpr int STRIDE = LENQ + 4;
  f32x4 acc[D3*4];
  run_chain<D3, IF, Is...>(acc, wt, xsw, yv, lmod, ldiv);

  const int es2 = lane>>2, oct2 = lane&3;
  #pragma unroll
  for(int q=0; q<4; ++q){
    #pragma unroll
    for(int rt=0; rt<D3; ++rt)
      #pragma unroll
      for(int j=0;j<4;++j)
        ost[(ldiv*4+j)*STRIDE + lmod*D3 + rt] = acc[rt*4 + q][j];
    lds_fence();
    #pragma unroll
    for(int c=0;c<LENQ/16;++c){
      *(float4*)(outb + (long)es2*576 + KOFF + q*LENQ + c*16 + oct2*4) =
        *(const float4*)(ost + es2*STRIDE + c*16 + oct2*4);
    }
    lds_fence();
  }
  store_drain();                    // once per kgroup
}

// ---------------- main kernel: TWO waves per block, 16 shared edges ----------
__global__ __launch_bounds__(128,2) void tp_main(const float* __restrict__ x,
                                                 const float* __restrict__ y,
                                                 const uint16_t* __restrict__ wt,
                                                 float* __restrict__ out)
{
  __shared__ char  xlds[18432] __attribute__((aligned(16)));
  __shared__ float ost0[832]   __attribute__((aligned(16)));   // wave0: k0/k1
  __shared__ float ost1[1344]  __attribute__((aligned(16)));   // wave1: k2
  const int tid  = threadIdx.x;
  const int wave = tid>>6, lane = tid&63;
  const int lmod = lane&15, ldiv = lane>>4;
  const long nE = (long)blockIdx.x*NE_W;
  char* xsw = xlds;

  // per-lane y: compute edge e = lmod (both waves need it)
  float yv[9];
  {
    const float* yp = y + (nE + lmod)*9;
    #pragma unroll
    for(int q=0;q<9;++q) yv[q] = yp[q];
  }

  // ---- stage x (16 edges) with ALL 128 threads: R7-PROVEN 8-lane/edge pack ----
  {
    const int es = tid>>3, oct = tid&7;          // edge 0..15, u-block 0..7
    const float* xr = x + (nE+es)*576;
    uint32_t xp[9][4];   // xp[pidx][a] = bf16 pair (u=oct*8+2a, u=oct*8+2a+1)

    const float4 a0 = *(const float4*)(xr + oct*8);
    const float4 a1 = *(const float4*)(xr + oct*8 + 4);
    xp[0][0]=pk2c(a0.x,a0.y); xp[0][1]=pk2c(a0.z,a0.w);
    xp[0][2]=pk2c(a1.x,a1.y); xp[0][3]=pk2c(a1.z,a1.w);
    float f1[24];
    {
      const float4* p1 = (const float4*)(xr + 64 + oct*24);
      #pragma unroll
      for(int i=0;i<6;++i){ float4 v=p1[i]; f1[4*i]=v.x; f1[4*i+1]=v.y; f1[4*i+2]=v.z; f1[4*i+3]=v.w; }
    }
    #pragma unroll
    for(int p=0;p<3;++p)
      #pragma unroll
      for(int a=0;a<4;++a) xp[1+p][a] = pk2c(f1[(2*a)*3+p], f1[(2*a+1)*3+p]);
    float f2[40];
    {
      const float4* p2 = (const float4*)(xr + 256 + oct*40);
      #pragma unroll
      for(int i=0;i<10;++i){ float4 v=p2[i]; f2[4*i]=v.x; f2[4*i+1]=v.y; f2[4*i+2]=v.z; f2[4*i+3]=v.w; }
    }
    #pragma unroll
    for(int p=0;p<5;++p)
      #pragma unroll
      for(int a=0;a<4;++a) xp[4+p][a] = pk2c(f2[(2*a)*5+p], f2[(2*a+1)*5+p]);

    // 9 ds_write_b128: row rho = es*9+pidx, chunk oct at position oct^(rho&7)
    #pragma unroll
    for(int pidx=0;pidx<9;++pidx){
      const int rho = es*9 + pidx;
      *(u32x4*)(xsw + rho*128 + ((oct ^ (rho&7))<<4)) = *(const u32x4*)&xp[pidx][0];
    }
  }

  // the ONE real barrier: both waves' staging visible to both waves
  __syncthreads();

  float* outb = out + nE*576;
  if(wave == 0){
    // k0 (l3=0, koff 0):   I = 0:(000) 4:(110) 9:(220)   [h-split, stride 36]
    kgroup_h<0,  1, 0,4,9   >(wt, xsw, yv, outb, ost0, lane, lmod, ldiv);
    // k1 (l3=1, koff 64):  I = 1:(011) 3:(101) 6:(121) 8:(211) [q-split, 52]
    kgroup_q<64, 3, 1,3,6,8 >(wt, xsw, yv, outb, ost0, lane, lmod, ldiv);
  } else {
    // k2 (l3=2, koff 256): I = 2:(022) 5:(112) 7:(202) 10:(222) [q-split, 84]
    kgroup_q<256,5, 2,5,7,10>(wt, xsw, yv, outb, ost1, lane, lmod, ldiv);
  }
}

// ---------------- launch ----------------
extern "C" void kernel_launch(void* const* d_in, const int* in_sizes, int n_in,
                              void* d_out, int out_size, void* d_ws, size_t ws_size,
                              hipStream_t stream)
{
  const float* x = (const float*)d_in[0];
  const float* y = (const float*)d_in[1];
  const float* w = (const float*)d_in[2];
  uint16_t* wt = (uint16_t*)d_ws;                 // 11*4096*2 = 90112 B
  prep_w<<<176, 256, 0, stream>>>(w, wt);
  tp_main<<<NBLK, 128, 0, stream>>>(x, y, wt, (float*)d_out);
}